// Round 1
// baseline (6223.583 us; speedup 1.0000x reference)
//
#include <hip/hip_runtime.h>
#include <hip/hip_bf16.h>

// Problem constants
#define Bq 32
#define Tq 512
#define Dq 768
#define Mq 2048
#define Kq 32
#define Rq 128
#define Hq 1024
#define NROWS (Mq * Kq)   // 65536
#define CH 8192           // rows per chunk (256 mentions)
#define NCH (NROWS / CH)  // 8

__device__ __forceinline__ float gelu_tanh(float x) {
    float x3 = x * x * x;
    return 0.5f * x * (1.0f + tanhf(0.7978845608028654f * (x + 0.044715f * x3)));
}

// Block-wide reduce of two values (sum). 256 threads = 4 waves.
__device__ __forceinline__ void block_reduce2(float& a, float& b, float* sm) {
    #pragma unroll
    for (int off = 32; off > 0; off >>= 1) {
        a += __shfl_down(a, off, 64);
        b += __shfl_down(b, off, 64);
    }
    int lane = threadIdx.x & 63, wid = threadIdx.x >> 6;
    if (lane == 0) { sm[wid * 2] = a; sm[wid * 2 + 1] = b; }
    __syncthreads();
    if (threadIdx.x == 0) {
        float sa = 0.f, sb = 0.f;
        #pragma unroll
        for (int w = 0; w < 4; ++w) { sa += sm[w * 2]; sb += sm[w * 2 + 1]; }
        sm[0] = sa; sm[1] = sb;
    }
    __syncthreads();
    a = sm[0]; b = sm[1];
    __syncthreads();
}

// ---------------------------------------------------------------------------
// Gather start/end encodings and project: pmv[M,128] = concat(start,end)@vp_w + vp_b
// 8 mentions per block, 256 threads.
__global__ __launch_bounds__(256) void gather_vp_k(
    const float* __restrict__ enc, const int* __restrict__ bpos,
    const int* __restrict__ spos, const int* __restrict__ epos,
    const float* __restrict__ vp_w, const float* __restrict__ vp_b,
    float* __restrict__ pmv)
{
    __shared__ float x[8][1536];
    int m0 = blockIdx.x * 8;
    int tid = threadIdx.x;
    // cooperative gather: 8 mentions x 1536 floats = 3072 float4
    #pragma unroll
    for (int i = 0; i < 12; ++i) {
        int li = tid + i * 256;
        int j = li / 384;
        int q = li % 384;
        int m = m0 + j;
        int b = bpos[m];
        int pos = (q < 192) ? spos[m] : epos[m];
        int qq = (q < 192) ? q : q - 192;
        const float4* src = reinterpret_cast<const float4*>(enc + ((long)b * Tq + pos) * Dq) + qq;
        *reinterpret_cast<float4*>(&x[j][(q < 192 ? 0 : 768) + qq * 4]) = *src;
    }
    __syncthreads();
    int col = tid & 127;
    int mg = tid >> 7;  // 0 or 1 -> mentions [mg*4, mg*4+3]
    float acc[4] = {0.f, 0.f, 0.f, 0.f};
    for (int i = 0; i < 1536; ++i) {
        float w = vp_w[i * 128 + col];
        #pragma unroll
        for (int jj = 0; jj < 4; ++jj)
            acc[jj] = fmaf(x[mg * 4 + jj][i], w, acc[jj]);
    }
    float bcol = vp_b[col];
    #pragma unroll
    for (int jj = 0; jj < 4; ++jj)
        pmv[(m0 + mg * 4 + jj) * 128 + col] = acc[jj] + bcol;
}

// ---------------------------------------------------------------------------
// Generic f32 tiled GEMM: C[rows,N] = epi(A[rows,Kd] @ W[Kd,N] + bias)
// Tile 64x64, BK=16, 256 threads, 4x4 per-thread microtile.
// CONCAT: A row gr = row_base+r is concat(pmv[gr/32], rv[gr]) (128+128).
// ACT: gelu. RESID: += resid[r*N+c].
template <int ACT, int CONCAT, int RESID>
__global__ __launch_bounds__(256) void gemm_k(
    const float* __restrict__ A, const float* __restrict__ W,
    const float* __restrict__ bias, float* __restrict__ C,
    int Kd, int N,
    const float* __restrict__ resid,
    const float* __restrict__ pmv, const float* __restrict__ rv,
    int row_base)
{
    __shared__ float As[16][64];
    __shared__ float Ws[16][64];
    int tid = threadIdx.x;
    int r0 = blockIdx.x * 64, c0 = blockIdx.y * 64;
    int tx = tid & 15, ty = tid >> 4;
    float acc[4][4] = {};
    for (int k0 = 0; k0 < Kd; k0 += 16) {
        #pragma unroll
        for (int i = 0; i < 4; ++i) {
            int li = tid + i * 256;
            int r = li >> 4, kk = li & 15;
            int krow = k0 + kk;
            float v;
            if (CONCAT) {
                int gr = row_base + r0 + r;
                v = (krow < 128) ? pmv[(gr >> 5) * 128 + krow]
                                 : rv[gr * 128 + (krow - 128)];
            } else {
                v = A[(long)(r0 + r) * Kd + krow];
            }
            As[kk][r] = v;
        }
        #pragma unroll
        for (int i = 0; i < 4; ++i) {
            int li = tid + i * 256;
            int kk = li >> 6, c = li & 63;
            Ws[kk][c] = W[(long)(k0 + kk) * N + c0 + c];
        }
        __syncthreads();
        #pragma unroll
        for (int kk = 0; kk < 16; ++kk) {
            float4 a4 = *reinterpret_cast<const float4*>(&As[kk][ty * 4]);
            float4 b4 = *reinterpret_cast<const float4*>(&Ws[kk][tx * 4]);
            float av[4] = {a4.x, a4.y, a4.z, a4.w};
            float bv[4] = {b4.x, b4.y, b4.z, b4.w};
            #pragma unroll
            for (int i = 0; i < 4; ++i)
                #pragma unroll
                for (int j = 0; j < 4; ++j)
                    acc[i][j] = fmaf(av[i], bv[j], acc[i][j]);
        }
        __syncthreads();
    }
    #pragma unroll
    for (int i = 0; i < 4; ++i) {
        int r = r0 + ty * 4 + i;
        #pragma unroll
        for (int j = 0; j < 4; ++j) {
            int c = c0 + tx * 4 + j;
            float v = acc[i][j] + bias[c];
            if (ACT) v = gelu_tanh(v);
            if (RESID) v += resid[(long)r * N + c];
            C[(long)r * N + c] = v;
        }
    }
}

// ---------------------------------------------------------------------------
// Per-mention: LN each of its 32 cv rows (ac_ln), then pooled[m] = sum_k score*ln(cv)
// One block per mention-in-chunk (256 threads, 3 elems each of 768).
__global__ __launch_bounds__(256) void ln_pool_k(
    const float* __restrict__ cv, const float* __restrict__ scores,
    const float* __restrict__ ln_s, const float* __restrict__ ln_b,
    float* __restrict__ pooled, int mbase)
{
    __shared__ float sm[8];
    int lm = blockIdx.x;
    int gm = mbase + lm;
    int tid = threadIdx.x;
    float pool[3] = {0.f, 0.f, 0.f};
    float gs[3], gb[3];
    #pragma unroll
    for (int j = 0; j < 3; ++j) { gs[j] = ln_s[tid + j * 256]; gb[j] = ln_b[tid + j * 256]; }
    for (int k = 0; k < 32; ++k) {
        const float* row = cv + ((long)lm * 32 + k) * Dq;
        float v[3];
        float s = 0.f, ss = 0.f;
        #pragma unroll
        for (int j = 0; j < 3; ++j) {
            v[j] = row[tid + j * 256];
            s += v[j]; ss += v[j] * v[j];
        }
        block_reduce2(s, ss, sm);
        float mu = s * (1.0f / Dq);
        float var = ss * (1.0f / Dq) - mu * mu;
        float rstd = rsqrtf(var + 1e-12f);
        float sc = scores[gm * 32 + k];
        #pragma unroll
        for (int j = 0; j < 3; ++j) {
            float y = (v[j] - mu) * rstd * gs[j] + gb[j];
            pool[j] = fmaf(sc, y, pool[j]);
        }
    }
    #pragma unroll
    for (int j = 0; j < 3; ++j)
        pooled[(long)gm * Dq + tid + j * 256] = pool[j];
}

// ---------------------------------------------------------------------------
// Per-mention: y = LN(pu + pooled; pl_ln) * mask; atomicAdd into out[(b,s)] row.
__global__ __launch_bounds__(256) void ln_mask_scatter_k(
    const float* __restrict__ pu, const float* __restrict__ pooled,
    const float* __restrict__ ln_s, const float* __restrict__ ln_b,
    const float* __restrict__ mask,
    const int* __restrict__ bpos, const int* __restrict__ spos,
    float* __restrict__ out)
{
    __shared__ float sm[8];
    int m = blockIdx.x;
    int tid = threadIdx.x;
    float v[3];
    float s = 0.f, ss = 0.f;
    #pragma unroll
    for (int j = 0; j < 3; ++j) {
        int d = tid + j * 256;
        v[j] = pu[(long)m * Dq + d] + pooled[(long)m * Dq + d];
        s += v[j]; ss += v[j] * v[j];
    }
    block_reduce2(s, ss, sm);
    float mu = s * (1.0f / Dq);
    float var = ss * (1.0f / Dq) - mu * mu;
    float rstd = rsqrtf(var + 1e-12f);
    float mk = mask[m];
    long orow = ((long)bpos[m] * Tq + spos[m]) * Dq;
    #pragma unroll
    for (int j = 0; j < 3; ++j) {
        int d = tid + j * 256;
        float y = ((v[j] - mu) * rstd * ln_s[d] + ln_b[d]) * mk;
        atomicAdd(&out[orow + d], y);
    }
}

// ---------------------------------------------------------------------------
// Final in-place LN over each [768] row of out.
__global__ __launch_bounds__(256) void final_ln_k(
    float* __restrict__ out, const float* __restrict__ ln_s,
    const float* __restrict__ ln_b)
{
    __shared__ float sm[8];
    int tid = threadIdx.x;
    float* row = out + (long)blockIdx.x * Dq;
    float v[3];
    float s = 0.f, ss = 0.f;
    #pragma unroll
    for (int j = 0; j < 3; ++j) {
        v[j] = row[tid + j * 256];
        s += v[j]; ss += v[j] * v[j];
    }
    block_reduce2(s, ss, sm);
    float mu = s * (1.0f / Dq);
    float var = ss * (1.0f / Dq) - mu * mu;
    float rstd = rsqrtf(var + 1e-12f);
    #pragma unroll
    for (int j = 0; j < 3; ++j) {
        int d = tid + j * 256;
        row[d] = (v[j] - mu) * rstd * ln_s[d] + ln_b[d];
    }
}

// ---------------------------------------------------------------------------
extern "C" void kernel_launch(void* const* d_in, const int* in_sizes, int n_in,
                              void* d_out, int out_size, void* d_ws, size_t ws_size,
                              hipStream_t stream) {
    const float* enc    = (const float*)d_in[0];
    const float* rv     = (const float*)d_in[1];
    const float* scores = (const float*)d_in[2];
    const int*   bpos   = (const int*)d_in[3];
    const int*   spos   = (const int*)d_in[4];
    const int*   epos   = (const int*)d_in[5];
    const float* mask   = (const float*)d_in[6];
    const float* vp_w   = (const float*)d_in[7];
    const float* vp_b   = (const float*)d_in[8];
    const float* cm_w   = (const float*)d_in[9];
    const float* cm_b   = (const float*)d_in[10];
    const float* cd_w   = (const float*)d_in[11];
    const float* cd_b   = (const float*)d_in[12];
    const float* ac_w1  = (const float*)d_in[13];
    const float* ac_b1  = (const float*)d_in[14];
    const float* ac_w2  = (const float*)d_in[15];
    const float* ac_b2  = (const float*)d_in[16];
    const float* ac_ln_s = (const float*)d_in[17];
    const float* ac_ln_b = (const float*)d_in[18];
    const float* pl_w1  = (const float*)d_in[19];
    const float* pl_b1  = (const float*)d_in[20];
    const float* pl_w2  = (const float*)d_in[21];
    const float* pl_b2  = (const float*)d_in[22];
    const float* pl_ln_s = (const float*)d_in[23];
    const float* pl_ln_b = (const float*)d_in[24];
    const float* ln_s   = (const float*)d_in[25];
    const float* ln_b   = (const float*)d_in[26];
    float* out = (float*)d_out;

    // workspace layout (floats)
    float* ws     = (float*)d_ws;
    float* pmv    = ws;                           // 2048*128     = 262144
    float* pooled = pmv + (size_t)Mq * Rq;        // 2048*768     = 1572864
    float* hbuf   = pooled + (size_t)Mq * Dq;     // 8192*1024    = 8388608
    float* tbuf   = hbuf + (size_t)CH * Hq;       // 8192*768     = 6291456
    float* cvbuf  = tbuf + (size_t)CH * Dq;       // 8192*768     = 6291456
    // total ~91.2 MB

    // out = encoded_input (base for scatter-add)
    hipMemcpyAsync(out, enc, (size_t)Bq * Tq * Dq * sizeof(float),
                   hipMemcpyDeviceToDevice, stream);

    // pmv
    gather_vp_k<<<Mq / 8, 256, 0, stream>>>(enc, bpos, spos, epos, vp_w, vp_b, pmv);

    for (int c = 0; c < NCH; ++c) {
        int row_base = c * CH;
        int mbase = c * (CH / Kq);
        dim3 gA(CH / 64, Hq / 64);
        // h1 = gelu(concat(pmv, rv) @ cm_w + cm_b)
        gemm_k<1, 1, 0><<<gA, 256, 0, stream>>>(nullptr, cm_w, cm_b, hbuf,
                                                2 * Rq, Hq, nullptr, pmv, rv, row_base);
        dim3 gB(CH / 64, Dq / 64);
        // t = h1 @ cd_w + cd_b
        gemm_k<0, 0, 0><<<gB, 256, 0, stream>>>(hbuf, cd_w, cd_b, tbuf,
                                                Hq, Dq, nullptr, nullptr, nullptr, 0);
        // h2 = gelu(t @ ac_w1 + ac_b1)   (overwrites hbuf)
        gemm_k<1, 0, 0><<<gA, 256, 0, stream>>>(tbuf, ac_w1, ac_b1, hbuf,
                                                Dq, Hq, nullptr, nullptr, nullptr, 0);
        // cv_pre = h2 @ ac_w2 + ac_b2 + t
        gemm_k<0, 0, 1><<<gB, 256, 0, stream>>>(hbuf, ac_w2, ac_b2, cvbuf,
                                                Hq, Dq, tbuf, nullptr, nullptr, 0);
        // LN + score-weighted pool -> pooled[mbase..mbase+255]
        ln_pool_k<<<CH / Kq, 256, 0, stream>>>(cvbuf, scores, ac_ln_s, ac_ln_b,
                                               pooled, mbase);
    }

    // pooled MLP: ph = gelu(pooled @ pl_w1 + pl_b1); pu = ph @ pl_w2 + pl_b2
    dim3 g5(Mq / 64, Hq / 64);
    gemm_k<1, 0, 0><<<g5, 256, 0, stream>>>(pooled, pl_w1, pl_b1, hbuf,
                                            Dq, Hq, nullptr, nullptr, nullptr, 0);
    dim3 g6(Mq / 64, Dq / 64);
    gemm_k<0, 0, 0><<<g6, 256, 0, stream>>>(hbuf, pl_w2, pl_b2, tbuf,
                                            Hq, Dq, nullptr, nullptr, nullptr, 0);

    // LN(pu + pooled) * mask, scatter-add into out
    ln_mask_scatter_k<<<Mq, 256, 0, stream>>>(tbuf, pooled, pl_ln_s, pl_ln_b,
                                              mask, bpos, spos, out);

    // final LN over every row of out
    final_ln_k<<<Bq * Tq, 256, 0, stream>>>(out, ln_s, ln_b);
}

// Round 2
// 1163.296 us; speedup vs baseline: 5.3500x; 5.3500x over previous
//
#include <hip/hip_runtime.h>
#include <hip/hip_bf16.h>

// Problem constants
#define Bq 32
#define Tq 512
#define Dq 768
#define Mq 2048
#define Kq 32
#define Rq 128
#define Hq 1024
#define NROWS (Mq * Kq)   // 65536
#define CH 8192           // rows per chunk (256 mentions)
#define NCH (NROWS / CH)  // 8

typedef short short8 __attribute__((ext_vector_type(8)));
typedef float f32x4 __attribute__((ext_vector_type(4)));

__device__ __forceinline__ unsigned short f2bf(float f) {
    union { float f; unsigned u; } v; v.f = f;
    unsigned r = v.u + 0x7FFFu + ((v.u >> 16) & 1u);   // RNE
    return (unsigned short)(r >> 16);
}
__device__ __forceinline__ float bf2f(unsigned short h) {
    union { unsigned u; float f; } v; v.u = ((unsigned)h) << 16;
    return v.f;
}
// gelu(tanh approx) = x * sigmoid(2*0.79788456*(x + 0.044715 x^3))
__device__ __forceinline__ float gelu_f(float x) {
    float u = x * (1.5957691216057308f + 0.07135481622212034f * x * x);
    return x / (1.0f + __expf(-u));
}

// Block-wide reduce of two values (sum). 256 threads = 4 waves.
__device__ __forceinline__ void block_reduce2(float& a, float& b, float* sm) {
    #pragma unroll
    for (int off = 32; off > 0; off >>= 1) {
        a += __shfl_down(a, off, 64);
        b += __shfl_down(b, off, 64);
    }
    int lane = threadIdx.x & 63, wid = threadIdx.x >> 6;
    if (lane == 0) { sm[wid * 2] = a; sm[wid * 2 + 1] = b; }
    __syncthreads();
    if (threadIdx.x == 0) {
        float sa = 0.f, sb = 0.f;
        #pragma unroll
        for (int w = 0; w < 4; ++w) { sa += sm[w * 2]; sb += sm[w * 2 + 1]; }
        sm[0] = sa; sm[1] = sb;
    }
    __syncthreads();
    a = sm[0]; b = sm[1];
    __syncthreads();
}

// ---------------------------------------------------------------------------
// Weight transpose + f32->bf16: Wt[n][k] = bf16(W[k][n])
__global__ __launch_bounds__(256) void wtrans_k(
    const float* __restrict__ W, unsigned short* __restrict__ Wt, int K, int N)
{
    __shared__ unsigned short t[32][33];
    int n0 = blockIdx.x * 32, k0 = blockIdx.y * 32;
    int tx = threadIdx.x & 31, ty = threadIdx.x >> 5;
    #pragma unroll
    for (int i = 0; i < 32; i += 8)
        t[ty + i][tx] = f2bf(W[(long)(k0 + ty + i) * N + n0 + tx]);
    __syncthreads();
    #pragma unroll
    for (int i = 0; i < 32; i += 8)
        Wt[(long)(n0 + ty + i) * K + k0 + tx] = t[tx][ty + i];
}

// ---------------------------------------------------------------------------
// Gather start/end encodings and project: pmv[M,128] = concat(start,end)@vp_w + vp_b
// 8 mentions per block, 256 threads. Output bf16.
__global__ __launch_bounds__(256) void gather_vp_k(
    const float* __restrict__ enc, const int* __restrict__ bpos,
    const int* __restrict__ spos, const int* __restrict__ epos,
    const float* __restrict__ vp_w, const float* __restrict__ vp_b,
    unsigned short* __restrict__ pmvb)
{
    __shared__ float x[8][1536];
    int m0 = blockIdx.x * 8;
    int tid = threadIdx.x;
    #pragma unroll
    for (int i = 0; i < 12; ++i) {
        int li = tid + i * 256;
        int j = li / 384;
        int q = li % 384;
        int m = m0 + j;
        int b = bpos[m];
        int pos = (q < 192) ? spos[m] : epos[m];
        int qq = (q < 192) ? q : q - 192;
        const float4* src = reinterpret_cast<const float4*>(enc + ((long)b * Tq + pos) * Dq) + qq;
        *reinterpret_cast<float4*>(&x[j][(q < 192 ? 0 : 768) + qq * 4]) = *src;
    }
    __syncthreads();
    int col = tid & 127;
    int mg = tid >> 7;
    float acc[4] = {0.f, 0.f, 0.f, 0.f};
    for (int i = 0; i < 1536; ++i) {
        float w = vp_w[i * 128 + col];
        #pragma unroll
        for (int jj = 0; jj < 4; ++jj)
            acc[jj] = fmaf(x[mg * 4 + jj][i], w, acc[jj]);
    }
    float bcol = vp_b[col];
    #pragma unroll
    for (int jj = 0; jj < 4; ++jj)
        pmvb[(m0 + mg * 4 + jj) * 128 + col] = f2bf(acc[jj] + bcol);
}

// ---------------------------------------------------------------------------
// Build per-chunk concat input [CH][256] bf16: row gr -> [pmv[gr/32] | rv[gr]]
__global__ __launch_bounds__(256) void concat_k(
    const unsigned short* __restrict__ pmvb, const float* __restrict__ rv,
    unsigned short* __restrict__ out, int row_base)
{
    int i = blockIdx.x * 256 + threadIdx.x;   // CH*32 threads, 8 elems each
    int row = i >> 5;
    int seg = (i & 31) * 8;
    int gr = row_base + row;
    if (seg < 128) {
        *(short8*)(out + (long)row * 256 + seg) =
            *(const short8*)(pmvb + (long)(gr >> 5) * 128 + seg);
    } else {
        const float* s = rv + (long)gr * 128 + (seg - 128);
        unsigned short v[8];
        #pragma unroll
        for (int j = 0; j < 8; ++j) v[j] = f2bf(s[j]);
        *(short8*)(out + (long)row * 256 + seg) = *(short8*)v;
    }
}

// ---------------------------------------------------------------------------
// bf16 MFMA GEMM: C[rows][N] = epi(A[rows][Kd] @ Wt[N][Kd]^T + bias)
// 128x128 tile, BK=32, 4 waves (2x2), 16x16x32 MFMA, f32 accumulate.
// global_load_lds (16B) into linear [128][32] LDS tiles; conflict-free ds_read_b128.
template <int ACT, int OUT_BF16, int RESID>
__global__ __launch_bounds__(256) void mgemm_k(
    const unsigned short* __restrict__ A,    // [rows][Kd] bf16
    const unsigned short* __restrict__ Wt,   // [N][Kd] bf16
    const float* __restrict__ bias,          // [N]
    void* __restrict__ Cout,                 // [rows][N] bf16 or f32
    const unsigned short* __restrict__ resid,// [rows][N] bf16
    int Kd, int N)
{
    __shared__ __align__(16) unsigned short AsLin[128 * 32];
    __shared__ __align__(16) unsigned short BsLin[128 * 32];
    const int tid = threadIdx.x;
    const int w = tid >> 6, lane = tid & 63;
    const int wr = w >> 1, wc = w & 1;
    const int lr = lane & 15, lk = lane >> 4;
    const long r0 = (long)blockIdx.x * 128;
    const int c0 = blockIdx.y * 128;

    f32x4 acc[4][4] = {};

    for (int k0 = 0; k0 < Kd; k0 += 32) {
        #pragma unroll
        for (int cc = 0; cc < 2; ++cc) {
            int idx = (w * 2 + cc) * 64 + lane;       // 0..511
            int row = idx >> 2, kc = idx & 3;
            const unsigned short* ga = A + (r0 + row) * Kd + k0 + kc * 8;
            __builtin_amdgcn_global_load_lds(
                (const __attribute__((address_space(1))) void*)ga,
                (__attribute__((address_space(3))) void*)(AsLin + (w * 2 + cc) * 512),
                16, 0, 0);
            const unsigned short* gb = Wt + (long)(c0 + row) * Kd + k0 + kc * 8;
            __builtin_amdgcn_global_load_lds(
                (const __attribute__((address_space(1))) void*)gb,
                (__attribute__((address_space(3))) void*)(BsLin + (w * 2 + cc) * 512),
                16, 0, 0);
        }
        __syncthreads();   // compiler emits vmcnt(0) drain before barrier
        short8 af[4], bv[4];
        #pragma unroll
        for (int m = 0; m < 4; ++m)
            af[m] = *(const short8*)(AsLin + (wr * 64 + m * 16 + lr) * 32 + lk * 8);
        #pragma unroll
        for (int n = 0; n < 4; ++n)
            bv[n] = *(const short8*)(BsLin + (wc * 64 + n * 16 + lr) * 32 + lk * 8);
        #pragma unroll
        for (int m = 0; m < 4; ++m)
            #pragma unroll
            for (int n = 0; n < 4; ++n)
                acc[m][n] = __builtin_amdgcn_mfma_f32_16x16x32_bf16(
                    af[m], bv[n], acc[m][n], 0, 0, 0);
        __syncthreads();
    }

    // epilogue: C/D layout col=lane&15, row=(lane>>4)*4+reg  [m89/m91 verified]
    const int cb = c0 + wc * 64;
    #pragma unroll
    for (int n = 0; n < 4; ++n) {
        const int c = cb + n * 16 + lr;
        const float bc = bias[c];
        #pragma unroll
        for (int m = 0; m < 4; ++m) {
            const long r = r0 + wr * 64 + m * 16 + lk * 4;
            #pragma unroll
            for (int j = 0; j < 4; ++j) {
                float v = acc[m][n][j] + bc;
                if (ACT) v = gelu_f(v);
                if (RESID) v += bf2f(resid[(r + j) * N + c]);
                if (OUT_BF16) ((unsigned short*)Cout)[(r + j) * N + c] = f2bf(v);
                else          ((float*)Cout)[(r + j) * N + c] = v;
            }
        }
    }
}

// ---------------------------------------------------------------------------
// Per-mention: LN each of its 32 cv rows (ac_ln), pooled[m] = sum_k score*ln(cv).
// Writes pooled as f32 (for later residual) and bf16 (for next GEMM).
__global__ __launch_bounds__(256) void ln_pool_k(
    const float* __restrict__ cv, const float* __restrict__ scores,
    const float* __restrict__ ln_s, const float* __restrict__ ln_b,
    float* __restrict__ pooledf, unsigned short* __restrict__ pooledb, int mbase)
{
    __shared__ float sm[8];
    int lm = blockIdx.x;
    int gm = mbase + lm;
    int tid = threadIdx.x;
    float pool[3] = {0.f, 0.f, 0.f};
    float gs[3], gb[3];
    #pragma unroll
    for (int j = 0; j < 3; ++j) { gs[j] = ln_s[tid + j * 256]; gb[j] = ln_b[tid + j * 256]; }
    for (int k = 0; k < 32; ++k) {
        const float* row = cv + ((long)lm * 32 + k) * Dq;
        float v[3];
        float s = 0.f, ss = 0.f;
        #pragma unroll
        for (int j = 0; j < 3; ++j) {
            v[j] = row[tid + j * 256];
            s += v[j]; ss += v[j] * v[j];
        }
        block_reduce2(s, ss, sm);
        float mu = s * (1.0f / Dq);
        float var = ss * (1.0f / Dq) - mu * mu;
        float rstd = rsqrtf(var + 1e-12f);
        float sc = scores[gm * 32 + k];
        #pragma unroll
        for (int j = 0; j < 3; ++j) {
            float y = (v[j] - mu) * rstd * gs[j] + gb[j];
            pool[j] = fmaf(sc, y, pool[j]);
        }
    }
    #pragma unroll
    for (int j = 0; j < 3; ++j) {
        pooledf[(long)gm * Dq + tid + j * 256] = pool[j];
        pooledb[(long)gm * Dq + tid + j * 256] = f2bf(pool[j]);
    }
}

// ---------------------------------------------------------------------------
// Per-mention: y = LN(pu + pooled; pl_ln) * mask; atomicAdd into out[(b,s)] row.
__global__ __launch_bounds__(256) void ln_mask_scatter_k(
    const float* __restrict__ pu, const float* __restrict__ pooled,
    const float* __restrict__ ln_s, const float* __restrict__ ln_b,
    const float* __restrict__ mask,
    const int* __restrict__ bpos, const int* __restrict__ spos,
    float* __restrict__ out)
{
    __shared__ float sm[8];
    int m = blockIdx.x;
    int tid = threadIdx.x;
    float v[3];
    float s = 0.f, ss = 0.f;
    #pragma unroll
    for (int j = 0; j < 3; ++j) {
        int d = tid + j * 256;
        v[j] = pu[(long)m * Dq + d] + pooled[(long)m * Dq + d];
        s += v[j]; ss += v[j] * v[j];
    }
    block_reduce2(s, ss, sm);
    float mu = s * (1.0f / Dq);
    float var = ss * (1.0f / Dq) - mu * mu;
    float rstd = rsqrtf(var + 1e-12f);
    float mk = mask[m];
    long orow = ((long)bpos[m] * Tq + spos[m]) * Dq;
    #pragma unroll
    for (int j = 0; j < 3; ++j) {
        int d = tid + j * 256;
        float y = ((v[j] - mu) * rstd * ln_s[d] + ln_b[d]) * mk;
        atomicAdd(&out[orow + d], y);
    }
}

// ---------------------------------------------------------------------------
// Final in-place LN over each [768] row of out.
__global__ __launch_bounds__(256) void final_ln_k(
    float* __restrict__ out, const float* __restrict__ ln_s,
    const float* __restrict__ ln_b)
{
    __shared__ float sm[8];
    int tid = threadIdx.x;
    float* row = out + (long)blockIdx.x * Dq;
    float v[3];
    float s = 0.f, ss = 0.f;
    #pragma unroll
    for (int j = 0; j < 3; ++j) {
        v[j] = row[tid + j * 256];
        s += v[j]; ss += v[j] * v[j];
    }
    block_reduce2(s, ss, sm);
    float mu = s * (1.0f / Dq);
    float var = ss * (1.0f / Dq) - mu * mu;
    float rstd = rsqrtf(var + 1e-12f);
    #pragma unroll
    for (int j = 0; j < 3; ++j) {
        int d = tid + j * 256;
        row[d] = (v[j] - mu) * rstd * ln_s[d] + ln_b[d];
    }
}

// ---------------------------------------------------------------------------
extern "C" void kernel_launch(void* const* d_in, const int* in_sizes, int n_in,
                              void* d_out, int out_size, void* d_ws, size_t ws_size,
                              hipStream_t stream) {
    const float* enc    = (const float*)d_in[0];
    const float* rv     = (const float*)d_in[1];
    const float* scores = (const float*)d_in[2];
    const int*   bpos   = (const int*)d_in[3];
    const int*   spos   = (const int*)d_in[4];
    const int*   epos   = (const int*)d_in[5];
    const float* mask   = (const float*)d_in[6];
    const float* vp_w   = (const float*)d_in[7];
    const float* vp_b   = (const float*)d_in[8];
    const float* cm_w   = (const float*)d_in[9];
    const float* cm_b   = (const float*)d_in[10];
    const float* cd_w   = (const float*)d_in[11];
    const float* cd_b   = (const float*)d_in[12];
    const float* ac_w1  = (const float*)d_in[13];
    const float* ac_b1  = (const float*)d_in[14];
    const float* ac_w2  = (const float*)d_in[15];
    const float* ac_b2  = (const float*)d_in[16];
    const float* ac_ln_s = (const float*)d_in[17];
    const float* ac_ln_b = (const float*)d_in[18];
    const float* pl_w1  = (const float*)d_in[19];
    const float* pl_b1  = (const float*)d_in[20];
    const float* pl_w2  = (const float*)d_in[21];
    const float* pl_b2  = (const float*)d_in[22];
    const float* pl_ln_s = (const float*)d_in[23];
    const float* pl_ln_b = (const float*)d_in[24];
    const float* ln_s   = (const float*)d_in[25];
    const float* ln_b   = (const float*)d_in[26];
    float* out = (float*)d_out;

    // workspace layout (bytes), ~80 MB
    char* wsb = (char*)d_ws;
    unsigned short* wt_cm = (unsigned short*)wsb; wsb += (size_t)1024 * 256 * 2;
    unsigned short* wt_cd = (unsigned short*)wsb; wsb += (size_t)768 * 1024 * 2;
    unsigned short* wt_a1 = (unsigned short*)wsb; wsb += (size_t)1024 * 768 * 2;
    unsigned short* wt_a2 = (unsigned short*)wsb; wsb += (size_t)768 * 1024 * 2;
    unsigned short* wt_p1 = (unsigned short*)wsb; wsb += (size_t)1024 * 768 * 2;
    unsigned short* wt_p2 = (unsigned short*)wsb; wsb += (size_t)768 * 1024 * 2;
    unsigned short* pmvb  = (unsigned short*)wsb; wsb += (size_t)Mq * Rq * 2;
    unsigned short* catb  = (unsigned short*)wsb; wsb += (size_t)CH * 256 * 2;
    unsigned short* hb    = (unsigned short*)wsb; wsb += (size_t)CH * Hq * 2;
    unsigned short* tb    = (unsigned short*)wsb; wsb += (size_t)CH * Dq * 2;
    float* cvf     = (float*)wsb; wsb += (size_t)CH * Dq * 4;
    float* pooledf = (float*)wsb; wsb += (size_t)Mq * Dq * 4;
    unsigned short* pooledb = (unsigned short*)wsb; wsb += (size_t)Mq * Dq * 2;
    float* puf     = (float*)wsb; wsb += (size_t)Mq * Dq * 4;

    // out = encoded_input (base for scatter-add)
    hipMemcpyAsync(out, enc, (size_t)Bq * Tq * Dq * sizeof(float),
                   hipMemcpyDeviceToDevice, stream);

    // weights -> bf16 transposed [N][K]
    wtrans_k<<<dim3(1024 / 32, 256 / 32), 256, 0, stream>>>(cm_w, wt_cm, 256, 1024);
    wtrans_k<<<dim3(768 / 32, 1024 / 32), 256, 0, stream>>>(cd_w, wt_cd, 1024, 768);
    wtrans_k<<<dim3(1024 / 32, 768 / 32), 256, 0, stream>>>(ac_w1, wt_a1, 768, 1024);
    wtrans_k<<<dim3(768 / 32, 1024 / 32), 256, 0, stream>>>(ac_w2, wt_a2, 1024, 768);
    wtrans_k<<<dim3(1024 / 32, 768 / 32), 256, 0, stream>>>(pl_w1, wt_p1, 768, 1024);
    wtrans_k<<<dim3(768 / 32, 1024 / 32), 256, 0, stream>>>(pl_w2, wt_p2, 1024, 768);

    // pmv (bf16)
    gather_vp_k<<<Mq / 8, 256, 0, stream>>>(enc, bpos, spos, epos, vp_w, vp_b, pmvb);

    for (int c = 0; c < NCH; ++c) {
        int row_base = c * CH;
        int mbase = c * (CH / Kq);
        concat_k<<<(CH * 32) / 256, 256, 0, stream>>>(pmvb, rv, catb, row_base);
        // h1 = gelu(cat @ cm_w + cm_b)            [CH,1024] bf16
        mgemm_k<1, 1, 0><<<dim3(CH / 128, Hq / 128), 256, 0, stream>>>(
            catb, wt_cm, cm_b, hb, nullptr, 2 * Rq, Hq);
        // t = h1 @ cd_w + cd_b                    [CH,768] bf16
        mgemm_k<0, 1, 0><<<dim3(CH / 128, Dq / 128), 256, 0, stream>>>(
            hb, wt_cd, cd_b, tb, nullptr, Hq, Dq);
        // h2 = gelu(t @ ac_w1 + ac_b1)            [CH,1024] bf16
        mgemm_k<1, 1, 0><<<dim3(CH / 128, Hq / 128), 256, 0, stream>>>(
            tb, wt_a1, ac_b1, hb, nullptr, Dq, Hq);
        // cv = h2 @ ac_w2 + ac_b2 + t             [CH,768] f32
        mgemm_k<0, 0, 1><<<dim3(CH / 128, Dq / 128), 256, 0, stream>>>(
            hb, wt_a2, ac_b2, cvf, tb, Hq, Dq);
        // LN + score-weighted pool
        ln_pool_k<<<CH / Kq, 256, 0, stream>>>(cvf, scores, ac_ln_s, ac_ln_b,
                                               pooledf, pooledb, mbase);
    }

    // pooled MLP
    mgemm_k<1, 1, 0><<<dim3(Mq / 128, Hq / 128), 256, 0, stream>>>(
        pooledb, wt_p1, pl_b1, hb, nullptr, Dq, Hq);
    mgemm_k<0, 0, 0><<<dim3(Mq / 128, Dq / 128), 256, 0, stream>>>(
        hb, wt_p2, pl_b2, puf, nullptr, Hq, Dq);

    // LN(pu + pooled) * mask, scatter-add into out
    ln_mask_scatter_k<<<Mq, 256, 0, stream>>>(puf, pooledf, pl_ln_s, pl_ln_b,
                                              mask, bpos, spos, out);

    // final LN over every row of out
    final_ln_k<<<Bq * Tq, 256, 0, stream>>>(out, ln_s, ln_b);
}

// Round 3
// 1005.901 us; speedup vs baseline: 6.1871x; 1.1565x over previous
//
#include <hip/hip_runtime.h>
#include <hip/hip_bf16.h>

// Problem constants
#define Bq 32
#define Tq 512
#define Dq 768
#define Mq 2048
#define Kq 32
#define Rq 128
#define Hq 1024
#define NROWS (Mq * Kq)   // 65536
#define CH 8192           // rows per chunk (256 mentions)
#define NCH (NROWS / CH)  // 8

typedef short short8 __attribute__((ext_vector_type(8)));
typedef float f32x4 __attribute__((ext_vector_type(4)));

__device__ __forceinline__ unsigned short f2bf(float f) {
    union { float f; unsigned u; } v; v.f = f;
    unsigned r = v.u + 0x7FFFu + ((v.u >> 16) & 1u);   // RNE
    return (unsigned short)(r >> 16);
}
__device__ __forceinline__ float bf2f(unsigned short h) {
    union { unsigned u; float f; } v; v.u = ((unsigned)h) << 16;
    return v.f;
}
// gelu(tanh approx) = x * sigmoid(2*0.79788456*(x + 0.044715 x^3))
__device__ __forceinline__ float gelu_f(float x) {
    float u = x * (1.5957691216057308f + 0.07135481622212034f * x * x);
    return x / (1.0f + __expf(-u));
}

// Block-wide reduce of two values (sum). 256 threads = 4 waves.
__device__ __forceinline__ void block_reduce2(float& a, float& b, float* sm) {
    #pragma unroll
    for (int off = 32; off > 0; off >>= 1) {
        a += __shfl_down(a, off, 64);
        b += __shfl_down(b, off, 64);
    }
    int lane = threadIdx.x & 63, wid = threadIdx.x >> 6;
    if (lane == 0) { sm[wid * 2] = a; sm[wid * 2 + 1] = b; }
    __syncthreads();
    if (threadIdx.x == 0) {
        float sa = 0.f, sb = 0.f;
        #pragma unroll
        for (int w = 0; w < 4; ++w) { sa += sm[w * 2]; sb += sm[w * 2 + 1]; }
        sm[0] = sa; sm[1] = sb;
    }
    __syncthreads();
    a = sm[0]; b = sm[1];
    __syncthreads();
}

// ---------------------------------------------------------------------------
// Weight transpose + f32->bf16: Wt[n][k] = bf16(W[k][n])
__global__ __launch_bounds__(256) void wtrans_k(
    const float* __restrict__ W, unsigned short* __restrict__ Wt, int K, int N)
{
    __shared__ unsigned short t[32][33];
    int n0 = blockIdx.x * 32, k0 = blockIdx.y * 32;
    int tx = threadIdx.x & 31, ty = threadIdx.x >> 5;
    #pragma unroll
    for (int i = 0; i < 32; i += 8)
        t[ty + i][tx] = f2bf(W[(long)(k0 + ty + i) * N + n0 + tx]);
    __syncthreads();
    #pragma unroll
    for (int i = 0; i < 32; i += 8)
        Wt[(long)(n0 + ty + i) * K + k0 + tx] = t[tx][ty + i];
}

// ---------------------------------------------------------------------------
// Gather concat(start,end) encodings as bf16: cat[m][1536]
// One block (192 thr) per mention; 8 elems per thread.
__global__ __launch_bounds__(192) void gather_enc_k(
    const float* __restrict__ enc, const int* __restrict__ bpos,
    const int* __restrict__ spos, const int* __restrict__ epos,
    unsigned short* __restrict__ cat)
{
    int m = blockIdx.x;
    int t = threadIdx.x;                 // 0..191
    int b = bpos[m];
    int pos = (t < 96) ? spos[m] : epos[m];
    int off = (t < 96) ? t * 8 : (t - 96) * 8;
    const float4* s = reinterpret_cast<const float4*>(enc + ((long)b * Tq + pos) * Dq + off);
    float4 a = s[0], c = s[1];
    unsigned short v[8] = {f2bf(a.x), f2bf(a.y), f2bf(a.z), f2bf(a.w),
                           f2bf(c.x), f2bf(c.y), f2bf(c.z), f2bf(c.w)};
    *(short8*)(cat + (long)m * 1536 + t * 8) = *(short8*)v;
}

// ---------------------------------------------------------------------------
// Build per-chunk concat input [CH][256] bf16: row gr -> [pmv[gr/32] | rv[gr]]
__global__ __launch_bounds__(256) void concat_k(
    const unsigned short* __restrict__ pmvb, const float* __restrict__ rv,
    unsigned short* __restrict__ out, int row_base)
{
    int i = blockIdx.x * 256 + threadIdx.x;   // CH*32 threads, 8 elems each
    int row = i >> 5;
    int seg = (i & 31) * 8;
    int gr = row_base + row;
    if (seg < 128) {
        *(short8*)(out + (long)row * 256 + seg) =
            *(const short8*)(pmvb + (long)(gr >> 5) * 128 + seg);
    } else {
        const float* s = rv + (long)gr * 128 + (seg - 128);
        unsigned short v[8];
        #pragma unroll
        for (int j = 0; j < 8; ++j) v[j] = f2bf(s[j]);
        *(short8*)(out + (long)row * 256 + seg) = *(short8*)v;
    }
}

// ---------------------------------------------------------------------------
// bf16 MFMA GEMM: C[rows][N] = epi(A[rows][Kd] @ Wt[N][Kd]^T + bias)
// 128x128 tile, BK=32, 4 waves (2x2), 16x16x32 MFMA, f32 accumulate.
// global_load_lds (16B) into linear [128][32] LDS tiles; conflict-free ds_read_b128.
template <int ACT, int OUT_BF16, int RESID>
__global__ __launch_bounds__(256) void mgemm_k(
    const unsigned short* __restrict__ A,    // [rows][Kd] bf16
    const unsigned short* __restrict__ Wt,   // [N][Kd] bf16
    const float* __restrict__ bias,          // [N]
    void* __restrict__ Cout,                 // [rows][N] bf16 or f32
    const unsigned short* __restrict__ resid,// [rows][N] bf16
    int Kd, int N)
{
    __shared__ __align__(16) unsigned short AsLin[128 * 32];
    __shared__ __align__(16) unsigned short BsLin[128 * 32];
    const int tid = threadIdx.x;
    const int w = tid >> 6, lane = tid & 63;
    const int wr = w >> 1, wc = w & 1;
    const int lr = lane & 15, lk = lane >> 4;
    const long r0 = (long)blockIdx.x * 128;
    const int c0 = blockIdx.y * 128;

    f32x4 acc[4][4] = {};

    for (int k0 = 0; k0 < Kd; k0 += 32) {
        #pragma unroll
        for (int cc = 0; cc < 2; ++cc) {
            int idx = (w * 2 + cc) * 64 + lane;       // 0..511
            int row = idx >> 2, kc = idx & 3;
            const unsigned short* ga = A + (r0 + row) * Kd + k0 + kc * 8;
            __builtin_amdgcn_global_load_lds(
                (const __attribute__((address_space(1))) void*)ga,
                (__attribute__((address_space(3))) void*)(AsLin + (w * 2 + cc) * 512),
                16, 0, 0);
            const unsigned short* gb = Wt + (long)(c0 + row) * Kd + k0 + kc * 8;
            __builtin_amdgcn_global_load_lds(
                (const __attribute__((address_space(1))) void*)gb,
                (__attribute__((address_space(3))) void*)(BsLin + (w * 2 + cc) * 512),
                16, 0, 0);
        }
        __syncthreads();   // compiler emits vmcnt(0) drain before barrier
        short8 af[4], bv[4];
        #pragma unroll
        for (int m = 0; m < 4; ++m)
            af[m] = *(const short8*)(AsLin + (wr * 64 + m * 16 + lr) * 32 + lk * 8);
        #pragma unroll
        for (int n = 0; n < 4; ++n)
            bv[n] = *(const short8*)(BsLin + (wc * 64 + n * 16 + lr) * 32 + lk * 8);
        #pragma unroll
        for (int m = 0; m < 4; ++m)
            #pragma unroll
            for (int n = 0; n < 4; ++n)
                acc[m][n] = __builtin_amdgcn_mfma_f32_16x16x32_bf16(
                    af[m], bv[n], acc[m][n], 0, 0, 0);
        __syncthreads();
    }

    // epilogue: C/D layout col=lane&15, row=(lane>>4)*4+reg  [m89/m91 verified]
    const int cb = c0 + wc * 64;
    #pragma unroll
    for (int n = 0; n < 4; ++n) {
        const int c = cb + n * 16 + lr;
        const float bc = bias[c];
        #pragma unroll
        for (int m = 0; m < 4; ++m) {
            const long r = r0 + wr * 64 + m * 16 + lk * 4;
            #pragma unroll
            for (int j = 0; j < 4; ++j) {
                float v = acc[m][n][j] + bc;
                if (ACT) v = gelu_f(v);
                if (RESID) v += bf2f(resid[(r + j) * N + c]);
                if (OUT_BF16) ((unsigned short*)Cout)[(r + j) * N + c] = f2bf(v);
                else          ((float*)Cout)[(r + j) * N + c] = v;
            }
        }
    }
}

// ---------------------------------------------------------------------------
// Per-mention: LN each of its 32 cv rows (ac_ln), pooled[m] = sum_k score*ln(cv).
// 512 threads = 8 waves; each wave owns 4 rows end-to-end (wave-level reduce
// only, no block barriers in the row loop). LDS combine at the end.
__global__ __launch_bounds__(512) void ln_pool_k(
    const float* __restrict__ cv, const float* __restrict__ scores,
    const float* __restrict__ ln_s, const float* __restrict__ ln_b,
    float* __restrict__ pooledf, unsigned short* __restrict__ pooledb, int mbase)
{
    __shared__ float part[8][768];
    int lm = blockIdx.x, gm = mbase + lm;
    int tid = threadIdx.x, lane = tid & 63, wid = tid >> 6;
    float gs[12], gb[12], pool[12];
    #pragma unroll
    for (int j = 0; j < 12; ++j) {
        gs[j] = ln_s[j * 64 + lane];
        gb[j] = ln_b[j * 64 + lane];
        pool[j] = 0.f;
    }
    #pragma unroll
    for (int i = 0; i < 4; ++i) {
        int k = wid * 4 + i;
        const float* row = cv + ((long)lm * 32 + k) * Dq;
        float v[12];
        float s = 0.f, ss = 0.f;
        #pragma unroll
        for (int j = 0; j < 12; ++j) {
            v[j] = row[j * 64 + lane];
            s += v[j]; ss += v[j] * v[j];
        }
        #pragma unroll
        for (int off = 32; off > 0; off >>= 1) {
            s  += __shfl_xor(s, off, 64);
            ss += __shfl_xor(ss, off, 64);
        }
        float mu = s * (1.0f / Dq);
        float var = ss * (1.0f / Dq) - mu * mu;
        float rstd = rsqrtf(var + 1e-12f);
        float sc = scores[gm * 32 + k];
        #pragma unroll
        for (int j = 0; j < 12; ++j)
            pool[j] = fmaf(sc, (v[j] - mu) * rstd * gs[j] + gb[j], pool[j]);
    }
    #pragma unroll
    for (int j = 0; j < 12; ++j) part[wid][j * 64 + lane] = pool[j];
    __syncthreads();
    for (int d = tid; d < Dq; d += 512) {
        float s = 0.f;
        #pragma unroll
        for (int w = 0; w < 8; ++w) s += part[w][d];
        pooledf[(long)gm * Dq + d] = s;
        pooledb[(long)gm * Dq + d] = f2bf(s);
    }
}

// ---------------------------------------------------------------------------
// Per-mention: y = LN(pu + pooled; pl_ln) * mask; atomicAdd into out[(b,s)] row.
__global__ __launch_bounds__(256) void ln_mask_scatter_k(
    const float* __restrict__ pu, const float* __restrict__ pooled,
    const float* __restrict__ ln_s, const float* __restrict__ ln_b,
    const float* __restrict__ mask,
    const int* __restrict__ bpos, const int* __restrict__ spos,
    float* __restrict__ out)
{
    __shared__ float sm[8];
    int m = blockIdx.x;
    int tid = threadIdx.x;
    float v[3];
    float s = 0.f, ss = 0.f;
    #pragma unroll
    for (int j = 0; j < 3; ++j) {
        int d = tid + j * 256;
        v[j] = pu[(long)m * Dq + d] + pooled[(long)m * Dq + d];
        s += v[j]; ss += v[j] * v[j];
    }
    block_reduce2(s, ss, sm);
    float mu = s * (1.0f / Dq);
    float var = ss * (1.0f / Dq) - mu * mu;
    float rstd = rsqrtf(var + 1e-12f);
    float mk = mask[m];
    long orow = ((long)bpos[m] * Tq + spos[m]) * Dq;
    #pragma unroll
    for (int j = 0; j < 3; ++j) {
        int d = tid + j * 256;
        float y = ((v[j] - mu) * rstd * ln_s[d] + ln_b[d]) * mk;
        atomicAdd(&out[orow + d], y);
    }
}

// ---------------------------------------------------------------------------
// Final in-place LN over each [768] row of out.
__global__ __launch_bounds__(256) void final_ln_k(
    float* __restrict__ out, const float* __restrict__ ln_s,
    const float* __restrict__ ln_b)
{
    __shared__ float sm[8];
    int tid = threadIdx.x;
    float* row = out + (long)blockIdx.x * Dq;
    float v[3];
    float s = 0.f, ss = 0.f;
    #pragma unroll
    for (int j = 0; j < 3; ++j) {
        v[j] = row[tid + j * 256];
        s += v[j]; ss += v[j] * v[j];
    }
    block_reduce2(s, ss, sm);
    float mu = s * (1.0f / Dq);
    float var = ss * (1.0f / Dq) - mu * mu;
    float rstd = rsqrtf(var + 1e-12f);
    #pragma unroll
    for (int j = 0; j < 3; ++j) {
        int d = tid + j * 256;
        row[d] = (v[j] - mu) * rstd * ln_s[d] + ln_b[d];
    }
}

// ---------------------------------------------------------------------------
extern "C" void kernel_launch(void* const* d_in, const int* in_sizes, int n_in,
                              void* d_out, int out_size, void* d_ws, size_t ws_size,
                              hipStream_t stream) {
    const float* enc    = (const float*)d_in[0];
    const float* rv     = (const float*)d_in[1];
    const float* scores = (const float*)d_in[2];
    const int*   bpos   = (const int*)d_in[3];
    const int*   spos   = (const int*)d_in[4];
    const int*   epos   = (const int*)d_in[5];
    const float* mask   = (const float*)d_in[6];
    const float* vp_w   = (const float*)d_in[7];
    const float* vp_b   = (const float*)d_in[8];
    const float* cm_w   = (const float*)d_in[9];
    const float* cm_b   = (const float*)d_in[10];
    const float* cd_w   = (const float*)d_in[11];
    const float* cd_b   = (const float*)d_in[12];
    const float* ac_w1  = (const float*)d_in[13];
    const float* ac_b1  = (const float*)d_in[14];
    const float* ac_w2  = (const float*)d_in[15];
    const float* ac_b2  = (const float*)d_in[16];
    const float* ac_ln_s = (const float*)d_in[17];
    const float* ac_ln_b = (const float*)d_in[18];
    const float* pl_w1  = (const float*)d_in[19];
    const float* pl_b1  = (const float*)d_in[20];
    const float* pl_w2  = (const float*)d_in[21];
    const float* pl_b2  = (const float*)d_in[22];
    const float* pl_ln_s = (const float*)d_in[23];
    const float* pl_ln_b = (const float*)d_in[24];
    const float* ln_s   = (const float*)d_in[25];
    const float* ln_b   = (const float*)d_in[26];
    float* out = (float*)d_out;

    // workspace layout (bytes) — identical footprint to round 2 (~83 MB known-safe)
    char* wsb = (char*)d_ws;
    unsigned short* wt_cm = (unsigned short*)wsb; wsb += (size_t)1024 * 256 * 2;
    unsigned short* wt_cd = (unsigned short*)wsb; wsb += (size_t)768 * 1024 * 2;
    unsigned short* wt_a1 = (unsigned short*)wsb; wsb += (size_t)1024 * 768 * 2;
    unsigned short* wt_a2 = (unsigned short*)wsb; wsb += (size_t)768 * 1024 * 2;
    unsigned short* wt_p1 = (unsigned short*)wsb; wsb += (size_t)1024 * 768 * 2;
    unsigned short* wt_p2 = (unsigned short*)wsb; wsb += (size_t)768 * 1024 * 2;
    unsigned short* pmvb  = (unsigned short*)wsb; wsb += (size_t)Mq * Rq * 2;
    unsigned short* catb  = (unsigned short*)wsb; wsb += (size_t)CH * 256 * 2;
    unsigned short* hb    = (unsigned short*)wsb; wsb += (size_t)CH * Hq * 2;
    unsigned short* tb    = (unsigned short*)wsb; wsb += (size_t)CH * Dq * 2;
    float* cvf     = (float*)wsb; wsb += (size_t)CH * Dq * 4;
    float* pooledf = (float*)wsb; wsb += (size_t)Mq * Dq * 4;
    unsigned short* pooledb = (unsigned short*)wsb; wsb += (size_t)Mq * Dq * 2;
    float* puf     = (float*)wsb; wsb += (size_t)Mq * Dq * 4;

    // aliases for buffers dead during the prologue:
    //  - wt_vp [128][1536] bf16 (384 KB) lives in hb (first written in chunk loop)
    //  - catenc [2048][1536] bf16 (6.3 MB) lives in cvf (first written in chunk loop)
    unsigned short* wt_vp  = hb;
    unsigned short* catenc = (unsigned short*)cvf;

    // out = encoded_input (base for scatter-add)
    hipMemcpyAsync(out, enc, (size_t)Bq * Tq * Dq * sizeof(float),
                   hipMemcpyDeviceToDevice, stream);

    // weights -> bf16 transposed [N][K]
    wtrans_k<<<dim3(1024 / 32, 256 / 32), 256, 0, stream>>>(cm_w, wt_cm, 256, 1024);
    wtrans_k<<<dim3(768 / 32, 1024 / 32), 256, 0, stream>>>(cd_w, wt_cd, 1024, 768);
    wtrans_k<<<dim3(1024 / 32, 768 / 32), 256, 0, stream>>>(ac_w1, wt_a1, 768, 1024);
    wtrans_k<<<dim3(768 / 32, 1024 / 32), 256, 0, stream>>>(ac_w2, wt_a2, 1024, 768);
    wtrans_k<<<dim3(1024 / 32, 768 / 32), 256, 0, stream>>>(pl_w1, wt_p1, 768, 1024);
    wtrans_k<<<dim3(768 / 32, 1024 / 32), 256, 0, stream>>>(pl_w2, wt_p2, 1024, 768);
    wtrans_k<<<dim3(128 / 32, 1536 / 32), 256, 0, stream>>>(vp_w, wt_vp, 1536, 128);

    // pmv = concat(start,end) @ vp_w + vp_b  as bf16 MFMA GEMM
    gather_enc_k<<<Mq, 192, 0, stream>>>(enc, bpos, spos, epos, catenc);
    mgemm_k<0, 1, 0><<<dim3(Mq / 128, 1), 256, 0, stream>>>(
        catenc, wt_vp, vp_b, pmvb, nullptr, 1536, Rq);

    for (int c = 0; c < NCH; ++c) {
        int row_base = c * CH;
        int mbase = c * (CH / Kq);
        concat_k<<<(CH * 32) / 256, 256, 0, stream>>>(pmvb, rv, catb, row_base);
        // h1 = gelu(cat @ cm_w + cm_b)            [CH,1024] bf16
        mgemm_k<1, 1, 0><<<dim3(CH / 128, Hq / 128), 256, 0, stream>>>(
            catb, wt_cm, cm_b, hb, nullptr, 2 * Rq, Hq);
        // t = h1 @ cd_w + cd_b                    [CH,768] bf16
        mgemm_k<0, 1, 0><<<dim3(CH / 128, Dq / 128), 256, 0, stream>>>(
            hb, wt_cd, cd_b, tb, nullptr, Hq, Dq);
        // h2 = gelu(t @ ac_w1 + ac_b1)            [CH,1024] bf16
        mgemm_k<1, 1, 0><<<dim3(CH / 128, Hq / 128), 256, 0, stream>>>(
            tb, wt_a1, ac_b1, hb, nullptr, Dq, Hq);
        // cv = h2 @ ac_w2 + ac_b2 + t             [CH,768] f32
        mgemm_k<0, 0, 1><<<dim3(CH / 128, Dq / 128), 256, 0, stream>>>(
            hb, wt_a2, ac_b2, cvf, tb, Hq, Dq);
        // LN + score-weighted pool
        ln_pool_k<<<CH / Kq, 512, 0, stream>>>(cvf, scores, ac_ln_s, ac_ln_b,
                                               pooledf, pooledb, mbase);
    }

    // pooled MLP
    mgemm_k<1, 1, 0><<<dim3(Mq / 128, Hq / 128), 256, 0, stream>>>(
        pooledb, wt_p1, pl_b1, hb, nullptr, Dq, Hq);
    mgemm_k<0, 0, 0><<<dim3(Mq / 128, Dq / 128), 256, 0, stream>>>(
        hb, wt_p2, pl_b2, puf, nullptr, Hq, Dq);

    // LN(pu + pooled) * mask, scatter-add into out
    ln_mask_scatter_k<<<Mq, 256, 0, stream>>>(puf, pooledf, pl_ln_s, pl_ln_b,
                                              mask, bpos, spos, out);

    // final LN over every row of out
    final_ln_k<<<Bq * Tq, 256, 0, stream>>>(out, ln_s, ln_b);
}

// Round 4
// 918.625 us; speedup vs baseline: 6.7749x; 1.0950x over previous
//
#include <hip/hip_runtime.h>
#include <hip/hip_bf16.h>

// Problem constants
#define Bq 32
#define Tq 512
#define Dq 768
#define Mq 2048
#define Kq 32
#define Rq 128
#define Hq 1024
#define NROWS (Mq * Kq)   // 65536
#define CH 16384          // rows per chunk (512 mentions)
#define NCH (NROWS / CH)  // 4

typedef short short8 __attribute__((ext_vector_type(8)));
typedef unsigned short ushort4v __attribute__((ext_vector_type(4)));
typedef float f32x4 __attribute__((ext_vector_type(4)));

__device__ __forceinline__ unsigned short f2bf(float f) {
    union { float f; unsigned u; } v; v.f = f;
    unsigned r = v.u + 0x7FFFu + ((v.u >> 16) & 1u);   // RNE
    return (unsigned short)(r >> 16);
}
__device__ __forceinline__ float bf2f(unsigned short h) {
    union { unsigned u; float f; } v; v.u = ((unsigned)h) << 16;
    return v.f;
}
// gelu(tanh approx) = x * sigmoid(2*0.79788456*(x + 0.044715 x^3))
__device__ __forceinline__ float gelu_f(float x) {
    float u = x * (1.5957691216057308f + 0.07135481622212034f * x * x);
    return x / (1.0f + __expf(-u));
}

// Block-wide reduce of two values (sum). 256 threads = 4 waves.
__device__ __forceinline__ void block_reduce2(float& a, float& b, float* sm) {
    #pragma unroll
    for (int off = 32; off > 0; off >>= 1) {
        a += __shfl_down(a, off, 64);
        b += __shfl_down(b, off, 64);
    }
    int lane = threadIdx.x & 63, wid = threadIdx.x >> 6;
    if (lane == 0) { sm[wid * 2] = a; sm[wid * 2 + 1] = b; }
    __syncthreads();
    if (threadIdx.x == 0) {
        float sa = 0.f, sb = 0.f;
        #pragma unroll
        for (int w = 0; w < 4; ++w) { sa += sm[w * 2]; sb += sm[w * 2 + 1]; }
        sm[0] = sa; sm[1] = sb;
    }
    __syncthreads();
    a = sm[0]; b = sm[1];
    __syncthreads();
}

// ---------------------------------------------------------------------------
// Weight transpose + f32->bf16: Wt[n][k] = bf16(W[k][n])
__global__ __launch_bounds__(256) void wtrans_k(
    const float* __restrict__ W, unsigned short* __restrict__ Wt, int K, int N)
{
    __shared__ unsigned short t[32][33];
    int n0 = blockIdx.x * 32, k0 = blockIdx.y * 32;
    int tx = threadIdx.x & 31, ty = threadIdx.x >> 5;
    #pragma unroll
    for (int i = 0; i < 32; i += 8)
        t[ty + i][tx] = f2bf(W[(long)(k0 + ty + i) * N + n0 + tx]);
    __syncthreads();
    #pragma unroll
    for (int i = 0; i < 32; i += 8)
        Wt[(long)(n0 + ty + i) * K + k0 + tx] = t[tx][ty + i];
}

// ---------------------------------------------------------------------------
// rv (f32) -> rvb (bf16), whole tensor [NROWS][128]
__global__ __launch_bounds__(256) void rv2bf_k(
    const float* __restrict__ rv, unsigned short* __restrict__ rvb)
{
    long i = ((long)blockIdx.x * 256 + threadIdx.x) * 8;
    float4 a = *reinterpret_cast<const float4*>(rv + i);
    float4 b = *reinterpret_cast<const float4*>(rv + i + 4);
    unsigned short v[8] = {f2bf(a.x), f2bf(a.y), f2bf(a.z), f2bf(a.w),
                           f2bf(b.x), f2bf(b.y), f2bf(b.z), f2bf(b.w)};
    *(short8*)(rvb + i) = *(short8*)v;
}

// ---------------------------------------------------------------------------
// Gather concat(start,end) encodings as bf16: cat[m][1536]
__global__ __launch_bounds__(192) void gather_enc_k(
    const float* __restrict__ enc, const int* __restrict__ bpos,
    const int* __restrict__ spos, const int* __restrict__ epos,
    unsigned short* __restrict__ cat)
{
    int m = blockIdx.x;
    int t = threadIdx.x;                 // 0..191
    int b = bpos[m];
    int pos = (t < 96) ? spos[m] : epos[m];
    int off = (t < 96) ? t * 8 : (t - 96) * 8;
    const float4* s = reinterpret_cast<const float4*>(enc + ((long)b * Tq + pos) * Dq + off);
    float4 a = s[0], c = s[1];
    unsigned short v[8] = {f2bf(a.x), f2bf(a.y), f2bf(a.z), f2bf(a.w),
                           f2bf(c.x), f2bf(c.y), f2bf(c.z), f2bf(c.w)};
    *(short8*)(cat + (long)m * 1536 + t * 8) = *(short8*)v;
}

// ---------------------------------------------------------------------------
// bf16 MFMA GEMM: C[rows][N] = epi(A[rows][Kd] @ Wt[N][Kd]^T + bias)
// 128x128 tile, BK=32, 4 waves (2x2), 16x16x32 MFMA, f32 accumulate.
// global_load_lds (16B) into linear [128][32] LDS tiles; conflict-free ds_read_b128.
// CONCAT: A row gr=row_base+r is [pmvb[gr/32] (128) | rvb[gr] (128)], Kd=256.
template <int ACT, int OUT_BF16, int RESID, int CONCAT>
__global__ __launch_bounds__(256) void mgemm_k(
    const unsigned short* __restrict__ A,    // [rows][Kd] bf16 (unused if CONCAT)
    const unsigned short* __restrict__ Wt,   // [N][Kd] bf16
    const float* __restrict__ bias,          // [N]
    void* __restrict__ Cout,                 // [rows][N] bf16 or f32
    const unsigned short* __restrict__ resid,// [rows][N] bf16
    int Kd, int N,
    const unsigned short* __restrict__ pmvb, // [M][128] bf16
    const unsigned short* __restrict__ rvb,  // [NROWS][128] bf16
    int row_base)
{
    __shared__ __align__(16) unsigned short AsLin[128 * 32];
    __shared__ __align__(16) unsigned short BsLin[128 * 32];
    const int tid = threadIdx.x;
    const int w = tid >> 6, lane = tid & 63;
    const int wr = w >> 1, wc = w & 1;
    const int lr = lane & 15, lk = lane >> 4;
    const long r0 = (long)blockIdx.x * 128;
    const int c0 = blockIdx.y * 128;

    f32x4 acc[4][4] = {};

    for (int k0 = 0; k0 < Kd; k0 += 32) {
        #pragma unroll
        for (int cc = 0; cc < 2; ++cc) {
            int idx = (w * 2 + cc) * 64 + lane;       // 0..511
            int row = idx >> 2, kc = idx & 3;
            int kcol = k0 + kc * 8;
            const unsigned short* ga;
            if (CONCAT) {
                long gr = row_base + r0 + row;
                ga = (kcol < 128) ? pmvb + ((gr >> 5) << 7) + kcol
                                  : rvb + (gr << 7) + (kcol - 128);
            } else {
                ga = A + (r0 + row) * Kd + kcol;
            }
            __builtin_amdgcn_global_load_lds(
                (const __attribute__((address_space(1))) void*)ga,
                (__attribute__((address_space(3))) void*)(AsLin + (w * 2 + cc) * 512),
                16, 0, 0);
            const unsigned short* gb = Wt + (long)(c0 + row) * Kd + kcol;
            __builtin_amdgcn_global_load_lds(
                (const __attribute__((address_space(1))) void*)gb,
                (__attribute__((address_space(3))) void*)(BsLin + (w * 2 + cc) * 512),
                16, 0, 0);
        }
        __syncthreads();   // compiler emits vmcnt(0) drain before barrier
        short8 af[4], bv[4];
        #pragma unroll
        for (int m = 0; m < 4; ++m)
            af[m] = *(const short8*)(AsLin + (wr * 64 + m * 16 + lr) * 32 + lk * 8);
        #pragma unroll
        for (int n = 0; n < 4; ++n)
            bv[n] = *(const short8*)(BsLin + (wc * 64 + n * 16 + lr) * 32 + lk * 8);
        #pragma unroll
        for (int m = 0; m < 4; ++m)
            #pragma unroll
            for (int n = 0; n < 4; ++n)
                acc[m][n] = __builtin_amdgcn_mfma_f32_16x16x32_bf16(
                    af[m], bv[n], acc[m][n], 0, 0, 0);
        __syncthreads();
    }

    // epilogue: C/D layout col=lane&15, row=(lane>>4)*4+reg  [m89/m91 verified]
    const int cb = c0 + wc * 64;
    #pragma unroll
    for (int n = 0; n < 4; ++n) {
        const int c = cb + n * 16 + lr;
        const float bc = bias[c];
        #pragma unroll
        for (int m = 0; m < 4; ++m) {
            const long r = r0 + wr * 64 + m * 16 + lk * 4;
            #pragma unroll
            for (int j = 0; j < 4; ++j) {
                float v = acc[m][n][j] + bc;
                if (ACT) v = gelu_f(v);
                if (RESID) v += bf2f(resid[(r + j) * N + c]);
                if (OUT_BF16) ((unsigned short*)Cout)[(r + j) * N + c] = f2bf(v);
                else          ((float*)Cout)[(r + j) * N + c] = v;
            }
        }
    }
}

// ---------------------------------------------------------------------------
// Stage A of LN+pool: each block handles 8 of a mention's 32 rows (1 row/wave),
// LN (ac_ln) + score-weight, writes partial sums. grid = (CH/32)*4.
__global__ __launch_bounds__(512) void ln_pool_part_k(
    const unsigned short* __restrict__ cvb, const float* __restrict__ scores,
    const float* __restrict__ ln_s, const float* __restrict__ ln_b,
    float* __restrict__ partial,   // [CH/32][4][768]
    int mbase)
{
    __shared__ float part[8][768];
    int lm = blockIdx.x >> 2, ks = blockIdx.x & 3;
    int gm = mbase + lm;
    int tid = threadIdx.x, lane = tid & 63, wid = tid >> 6;
    int k = ks * 8 + wid;
    const unsigned short* row = cvb + ((long)lm * 32 + k) * Dq;

    float v[12], gs[12], gb[12];
    float s = 0.f, ss = 0.f;
    #pragma unroll
    for (int j = 0; j < 3; ++j) {
        int col = j * 256 + lane * 4;
        ushort4v u = *(const ushort4v*)(row + col);
        float4 g = *reinterpret_cast<const float4*>(ln_s + col);
        float4 h = *reinterpret_cast<const float4*>(ln_b + col);
        #pragma unroll
        for (int t = 0; t < 4; ++t) {
            float x = bf2f(u[t]);
            v[j * 4 + t] = x;
            s += x; ss += x * x;
        }
        gs[j * 4 + 0] = g.x; gs[j * 4 + 1] = g.y; gs[j * 4 + 2] = g.z; gs[j * 4 + 3] = g.w;
        gb[j * 4 + 0] = h.x; gb[j * 4 + 1] = h.y; gb[j * 4 + 2] = h.z; gb[j * 4 + 3] = h.w;
    }
    #pragma unroll
    for (int off = 32; off > 0; off >>= 1) {
        s  += __shfl_xor(s, off, 64);
        ss += __shfl_xor(ss, off, 64);
    }
    float mu = s * (1.0f / Dq);
    float var = ss * (1.0f / Dq) - mu * mu;
    float rstd = rsqrtf(var + 1e-12f);
    float sc = scores[gm * 32 + k];
    #pragma unroll
    for (int j = 0; j < 3; ++j) {
        int col = j * 256 + lane * 4;
        #pragma unroll
        for (int t = 0; t < 4; ++t)
            part[wid][col + t] = sc * ((v[j * 4 + t] - mu) * rstd * gs[j * 4 + t] + gb[j * 4 + t]);
    }
    __syncthreads();
    for (int d = tid; d < Dq; d += 512) {
        float acc = 0.f;
        #pragma unroll
        for (int w = 0; w < 8; ++w) acc += part[w][d];
        partial[((long)lm * 4 + ks) * Dq + d] = acc;
    }
}

// Stage B: pooled[m] = sum of 4 partials. grid = CH/32.
__global__ __launch_bounds__(256) void ln_pool_comb_k(
    const float* __restrict__ partial, float* __restrict__ pooledf,
    unsigned short* __restrict__ pooledb, int mbase)
{
    int lm = blockIdx.x, gm = mbase + lm;
    int tid = threadIdx.x;
    for (int d = tid; d < Dq; d += 256) {
        const float* p = partial + (long)lm * 4 * Dq + d;
        float s = p[0] + p[Dq] + p[2 * Dq] + p[3 * Dq];
        pooledf[(long)gm * Dq + d] = s;
        pooledb[(long)gm * Dq + d] = f2bf(s);
    }
}

// ---------------------------------------------------------------------------
// Per-mention: y = LN(pu + pooled; pl_ln) * mask; atomicAdd into out[(b,s)] row.
__global__ __launch_bounds__(256) void ln_mask_scatter_k(
    const float* __restrict__ pu, const float* __restrict__ pooled,
    const float* __restrict__ ln_s, const float* __restrict__ ln_b,
    const float* __restrict__ mask,
    const int* __restrict__ bpos, const int* __restrict__ spos,
    float* __restrict__ out)
{
    __shared__ float sm[8];
    int m = blockIdx.x;
    int tid = threadIdx.x;
    float v[3];
    float s = 0.f, ss = 0.f;
    #pragma unroll
    for (int j = 0; j < 3; ++j) {
        int d = tid + j * 256;
        v[j] = pu[(long)m * Dq + d] + pooled[(long)m * Dq + d];
        s += v[j]; ss += v[j] * v[j];
    }
    block_reduce2(s, ss, sm);
    float mu = s * (1.0f / Dq);
    float var = ss * (1.0f / Dq) - mu * mu;
    float rstd = rsqrtf(var + 1e-12f);
    float mk = mask[m];
    long orow = ((long)bpos[m] * Tq + spos[m]) * Dq;
    #pragma unroll
    for (int j = 0; j < 3; ++j) {
        int d = tid + j * 256;
        float y = ((v[j] - mu) * rstd * ln_s[d] + ln_b[d]) * mk;
        atomicAdd(&out[orow + d], y);
    }
}

// ---------------------------------------------------------------------------
// Final in-place LN over each [768] row of out.
__global__ __launch_bounds__(256) void final_ln_k(
    float* __restrict__ out, const float* __restrict__ ln_s,
    const float* __restrict__ ln_b)
{
    __shared__ float sm[8];
    int tid = threadIdx.x;
    float* row = out + (long)blockIdx.x * Dq;
    float v[3];
    float s = 0.f, ss = 0.f;
    #pragma unroll
    for (int j = 0; j < 3; ++j) {
        v[j] = row[tid + j * 256];
        s += v[j]; ss += v[j] * v[j];
    }
    block_reduce2(s, ss, sm);
    float mu = s * (1.0f / Dq);
    float var = ss * (1.0f / Dq) - mu * mu;
    float rstd = rsqrtf(var + 1e-12f);
    #pragma unroll
    for (int j = 0; j < 3; ++j) {
        int d = tid + j * 256;
        row[d] = (v[j] - mu) * rstd * ln_s[d] + ln_b[d];
    }
}

// ---------------------------------------------------------------------------
extern "C" void kernel_launch(void* const* d_in, const int* in_sizes, int n_in,
                              void* d_out, int out_size, void* d_ws, size_t ws_size,
                              hipStream_t stream) {
    const float* enc    = (const float*)d_in[0];
    const float* rv     = (const float*)d_in[1];
    const float* scores = (const float*)d_in[2];
    const int*   bpos   = (const int*)d_in[3];
    const int*   spos   = (const int*)d_in[4];
    const int*   epos   = (const int*)d_in[5];
    const float* mask   = (const float*)d_in[6];
    const float* vp_w   = (const float*)d_in[7];
    const float* vp_b   = (const float*)d_in[8];
    const float* cm_w   = (const float*)d_in[9];
    const float* cm_b   = (const float*)d_in[10];
    const float* cd_w   = (const float*)d_in[11];
    const float* cd_b   = (const float*)d_in[12];
    const float* ac_w1  = (const float*)d_in[13];
    const float* ac_b1  = (const float*)d_in[14];
    const float* ac_w2  = (const float*)d_in[15];
    const float* ac_b2  = (const float*)d_in[16];
    const float* ac_ln_s = (const float*)d_in[17];
    const float* ac_ln_b = (const float*)d_in[18];
    const float* pl_w1  = (const float*)d_in[19];
    const float* pl_b1  = (const float*)d_in[20];
    const float* pl_w2  = (const float*)d_in[21];
    const float* pl_b2  = (const float*)d_in[22];
    const float* pl_ln_s = (const float*)d_in[23];
    const float* pl_ln_b = (const float*)d_in[24];
    const float* ln_s   = (const float*)d_in[25];
    const float* ln_b   = (const float*)d_in[26];
    float* out = (float*)d_out;

    // workspace layout (bytes), ~130 MB of the confirmed 256 MiB
    char* wsb = (char*)d_ws;
    unsigned short* wt_cm = (unsigned short*)wsb; wsb += (size_t)1024 * 256 * 2;
    unsigned short* wt_cd = (unsigned short*)wsb; wsb += (size_t)768 * 1024 * 2;
    unsigned short* wt_a1 = (unsigned short*)wsb; wsb += (size_t)1024 * 768 * 2;
    unsigned short* wt_a2 = (unsigned short*)wsb; wsb += (size_t)768 * 1024 * 2;
    unsigned short* wt_p1 = (unsigned short*)wsb; wsb += (size_t)1024 * 768 * 2;
    unsigned short* wt_p2 = (unsigned short*)wsb; wsb += (size_t)768 * 1024 * 2;
    unsigned short* wt_vp = (unsigned short*)wsb; wsb += (size_t)128 * 1536 * 2;
    unsigned short* pmvb  = (unsigned short*)wsb; wsb += (size_t)Mq * Rq * 2;
    unsigned short* rvb   = (unsigned short*)wsb; wsb += (size_t)NROWS * Rq * 2;
    unsigned short* catenc = (unsigned short*)wsb; wsb += (size_t)Mq * 1536 * 2;
    unsigned short* hb    = (unsigned short*)wsb; wsb += (size_t)CH * Hq * 2;
    unsigned short* tb    = (unsigned short*)wsb; wsb += (size_t)CH * Dq * 2;
    unsigned short* cvb   = (unsigned short*)wsb; wsb += (size_t)CH * Dq * 2;
    float* partial = (float*)wsb; wsb += (size_t)(CH / Kq) * 4 * Dq * 4;
    float* pooledf = (float*)wsb; wsb += (size_t)Mq * Dq * 4;
    unsigned short* pooledb = (unsigned short*)wsb; wsb += (size_t)Mq * Dq * 2;
    float* puf     = (float*)wsb; wsb += (size_t)Mq * Dq * 4;

    // out = encoded_input (base for scatter-add)
    hipMemcpyAsync(out, enc, (size_t)Bq * Tq * Dq * sizeof(float),
                   hipMemcpyDeviceToDevice, stream);

    // weights -> bf16 transposed [N][K]; rv -> bf16
    wtrans_k<<<dim3(1024 / 32, 256 / 32), 256, 0, stream>>>(cm_w, wt_cm, 256, 1024);
    wtrans_k<<<dim3(768 / 32, 1024 / 32), 256, 0, stream>>>(cd_w, wt_cd, 1024, 768);
    wtrans_k<<<dim3(1024 / 32, 768 / 32), 256, 0, stream>>>(ac_w1, wt_a1, 768, 1024);
    wtrans_k<<<dim3(768 / 32, 1024 / 32), 256, 0, stream>>>(ac_w2, wt_a2, 1024, 768);
    wtrans_k<<<dim3(1024 / 32, 768 / 32), 256, 0, stream>>>(pl_w1, wt_p1, 768, 1024);
    wtrans_k<<<dim3(768 / 32, 1024 / 32), 256, 0, stream>>>(pl_w2, wt_p2, 1024, 768);
    wtrans_k<<<dim3(128 / 32, 1536 / 32), 256, 0, stream>>>(vp_w, wt_vp, 1536, 128);
    rv2bf_k<<<(NROWS * Rq) / (256 * 8), 256, 0, stream>>>(rv, rvb);

    // pmv = concat(start,end) @ vp_w + vp_b  as bf16 MFMA GEMM
    gather_enc_k<<<Mq, 192, 0, stream>>>(enc, bpos, spos, epos, catenc);
    mgemm_k<0, 1, 0, 0><<<dim3(Mq / 128, 1), 256, 0, stream>>>(
        catenc, wt_vp, vp_b, pmvb, nullptr, 1536, Rq, nullptr, nullptr, 0);

    for (int c = 0; c < NCH; ++c) {
        int row_base = c * CH;
        int mbase = c * (CH / Kq);
        // h1 = gelu(concat(pmv,rv) @ cm_w + cm_b)   [CH,1024] bf16 (concat fused)
        mgemm_k<1, 1, 0, 1><<<dim3(CH / 128, Hq / 128), 256, 0, stream>>>(
            nullptr, wt_cm, cm_b, hb, nullptr, 2 * Rq, Hq, pmvb, rvb, row_base);
        // t = h1 @ cd_w + cd_b                      [CH,768] bf16
        mgemm_k<0, 1, 0, 0><<<dim3(CH / 128, Dq / 128), 256, 0, stream>>>(
            hb, wt_cd, cd_b, tb, nullptr, Hq, Dq, nullptr, nullptr, 0);
        // h2 = gelu(t @ ac_w1 + ac_b1)              [CH,1024] bf16
        mgemm_k<1, 1, 0, 0><<<dim3(CH / 128, Hq / 128), 256, 0, stream>>>(
            tb, wt_a1, ac_b1, hb, nullptr, Dq, Hq, nullptr, nullptr, 0);
        // cv = h2 @ ac_w2 + ac_b2 + t               [CH,768] bf16
        mgemm_k<0, 1, 1, 0><<<dim3(CH / 128, Dq / 128), 256, 0, stream>>>(
            hb, wt_a2, ac_b2, cvb, tb, Hq, Dq, nullptr, nullptr, 0);
        // LN + score-weighted pool (split-k over 4 blocks/mention, then combine)
        ln_pool_part_k<<<(CH / Kq) * 4, 512, 0, stream>>>(
            cvb, scores, ac_ln_s, ac_ln_b, partial, mbase);
        ln_pool_comb_k<<<CH / Kq, 256, 0, stream>>>(partial, pooledf, pooledb, mbase);
    }

    // pooled MLP
    mgemm_k<1, 1, 0, 0><<<dim3(Mq / 128, Hq / 128), 256, 0, stream>>>(
        pooledb, wt_p1, pl_b1, hb, nullptr, Dq, Hq, nullptr, nullptr, 0);
    mgemm_k<0, 0, 0, 0><<<dim3(Mq / 128, Dq / 128), 256, 0, stream>>>(
        hb, wt_p2, pl_b2, puf, nullptr, Hq, Dq, nullptr, nullptr, 0);

    // LN(pu + pooled) * mask, scatter-add into out
    ln_mask_scatter_k<<<Mq, 256, 0, stream>>>(puf, pooledf, pl_ln_s, pl_ln_b,
                                              mask, bpos, spos, out);

    // final LN over every row of out
    final_ln_k<<<Bq * Tq, 256, 0, stream>>>(out, ln_s, ln_b);
}

// Round 5
// 790.015 us; speedup vs baseline: 7.8778x; 1.1628x over previous
//
#include <hip/hip_runtime.h>
#include <hip/hip_bf16.h>

// Problem constants
#define Bq 32
#define Tq 512
#define Dq 768
#define Mq 2048
#define Kq 32
#define Rq 128
#define Hq 1024
#define NROWS (Mq * Kq)   // 65536
#define CH 16384          // rows per chunk (512 mentions)
#define NCH (NROWS / CH)  // 4

typedef short short8 __attribute__((ext_vector_type(8)));
typedef unsigned short ushort4v __attribute__((ext_vector_type(4)));
typedef float f32x4 __attribute__((ext_vector_type(4)));

__device__ __forceinline__ unsigned short f2bf(float f) {
    union { float f; unsigned u; } v; v.f = f;
    unsigned r = v.u + 0x7FFFu + ((v.u >> 16) & 1u);   // RNE
    return (unsigned short)(r >> 16);
}
__device__ __forceinline__ float bf2f(unsigned short h) {
    union { unsigned u; float f; } v; v.u = ((unsigned)h) << 16;
    return v.f;
}
// gelu(tanh approx) = x * sigmoid(2*0.79788456*(x + 0.044715 x^3))
__device__ __forceinline__ float gelu_f(float x) {
    float u = x * (1.5957691216057308f + 0.07135481622212034f * x * x);
    return x / (1.0f + __expf(-u));
}

// Block-wide reduce of two values (sum). 256 threads = 4 waves.
__device__ __forceinline__ void block_reduce2(float& a, float& b, float* sm) {
    #pragma unroll
    for (int off = 32; off > 0; off >>= 1) {
        a += __shfl_down(a, off, 64);
        b += __shfl_down(b, off, 64);
    }
    int lane = threadIdx.x & 63, wid = threadIdx.x >> 6;
    if (lane == 0) { sm[wid * 2] = a; sm[wid * 2 + 1] = b; }
    __syncthreads();
    if (threadIdx.x == 0) {
        float sa = 0.f, sb = 0.f;
        #pragma unroll
        for (int w = 0; w < 4; ++w) { sa += sm[w * 2]; sb += sm[w * 2 + 1]; }
        sm[0] = sa; sm[1] = sb;
    }
    __syncthreads();
    a = sm[0]; b = sm[1];
    __syncthreads();
}

// ---------------------------------------------------------------------------
// Weight transpose + f32->bf16: Wt[n][k] = bf16(W[k][n])
__global__ __launch_bounds__(256) void wtrans_k(
    const float* __restrict__ W, unsigned short* __restrict__ Wt, int K, int N)
{
    __shared__ unsigned short t[32][33];
    int n0 = blockIdx.x * 32, k0 = blockIdx.y * 32;
    int tx = threadIdx.x & 31, ty = threadIdx.x >> 5;
    #pragma unroll
    for (int i = 0; i < 32; i += 8)
        t[ty + i][tx] = f2bf(W[(long)(k0 + ty + i) * N + n0 + tx]);
    __syncthreads();
    #pragma unroll
    for (int i = 0; i < 32; i += 8)
        Wt[(long)(n0 + ty + i) * K + k0 + tx] = t[tx][ty + i];
}

// ---------------------------------------------------------------------------
// rv (f32) -> rvb (bf16), whole tensor [NROWS][128]
__global__ __launch_bounds__(256) void rv2bf_k(
    const float* __restrict__ rv, unsigned short* __restrict__ rvb)
{
    long i = ((long)blockIdx.x * 256 + threadIdx.x) * 8;
    float4 a = *reinterpret_cast<const float4*>(rv + i);
    float4 b = *reinterpret_cast<const float4*>(rv + i + 4);
    unsigned short v[8] = {f2bf(a.x), f2bf(a.y), f2bf(a.z), f2bf(a.w),
                           f2bf(b.x), f2bf(b.y), f2bf(b.z), f2bf(b.w)};
    *(short8*)(rvb + i) = *(short8*)v;
}

// ---------------------------------------------------------------------------
// Gather concat(start,end) encodings as bf16: cat[m][1536]
__global__ __launch_bounds__(192) void gather_enc_k(
    const float* __restrict__ enc, const int* __restrict__ bpos,
    const int* __restrict__ spos, const int* __restrict__ epos,
    unsigned short* __restrict__ cat)
{
    int m = blockIdx.x;
    int t = threadIdx.x;                 // 0..191
    int b = bpos[m];
    int pos = (t < 96) ? spos[m] : epos[m];
    int off = (t < 96) ? t * 8 : (t - 96) * 8;
    const float4* s = reinterpret_cast<const float4*>(enc + ((long)b * Tq + pos) * Dq + off);
    float4 a = s[0], c = s[1];
    unsigned short v[8] = {f2bf(a.x), f2bf(a.y), f2bf(a.z), f2bf(a.w),
                           f2bf(c.x), f2bf(c.y), f2bf(c.z), f2bf(c.w)};
    *(short8*)(cat + (long)m * 1536 + t * 8) = *(short8*)v;
}

// ---------------------------------------------------------------------------
// bf16 MFMA GEMM: C[rows][N] = epi(A[rows][Kd] @ Wt[N][Kd]^T + bias)
// 128x128 tile, BK=32, 4 waves (2x2), 16x16x32 MFMA, f32 accumulate.
// Depth-2 pipeline: double-buffered LDS, counted s_waitcnt vmcnt(4) so each
// tile's global_load_lds has ~2 iterations to land (T3/T4, m139-style raw
// barriers). Fragment addressing/epilogue identical to the verified round-2.
// CONCAT: A row gr=row_base+r is [pmvb[gr/32] (128) | rvb[gr] (128)], Kd=256.
template <int ACT, int OUT_BF16, int RESID, int CONCAT>
__global__ __launch_bounds__(256) void mgemm_k(
    const unsigned short* __restrict__ A,    // [rows][Kd] bf16 (unused if CONCAT)
    const unsigned short* __restrict__ Wt,   // [N][Kd] bf16
    const float* __restrict__ bias,          // [N]
    void* __restrict__ Cout,                 // [rows][N] bf16 or f32
    const unsigned short* __restrict__ resid,// [rows][N] bf16
    int Kd, int N,
    const unsigned short* __restrict__ pmvb, // [M][128] bf16
    const unsigned short* __restrict__ rvb,  // [NROWS][128] bf16
    int row_base)
{
    __shared__ __align__(16) unsigned short AsLin[2][128 * 32];
    __shared__ __align__(16) unsigned short BsLin[2][128 * 32];
    const int tid = threadIdx.x;
    const int w = tid >> 6, lane = tid & 63;
    const int wr = w >> 1, wc = w & 1;
    const int lr = lane & 15, lk = lane >> 4;
    const long r0 = (long)blockIdx.x * 128;
    const int c0 = blockIdx.y * 128;
    const int nt = Kd >> 5;

    // stage tile t into LDS buffer buf: 4 global_load_lds (16B) per thread
    auto stage = [&](int buf, int t) {
        const int k0 = t << 5;
        #pragma unroll
        for (int cc = 0; cc < 2; ++cc) {
            int idx = (w * 2 + cc) * 64 + lane;       // 0..511
            int row = idx >> 2, kc = idx & 3;
            int kcol = k0 + kc * 8;
            const unsigned short* ga;
            if (CONCAT) {
                long gr = row_base + r0 + row;
                ga = (kcol < 128) ? pmvb + ((gr >> 5) << 7) + kcol
                                  : rvb + (gr << 7) + (kcol - 128);
            } else {
                ga = A + (r0 + row) * Kd + kcol;
            }
            __builtin_amdgcn_global_load_lds(
                (const __attribute__((address_space(1))) void*)ga,
                (__attribute__((address_space(3))) void*)(&AsLin[buf][(w * 2 + cc) * 512]),
                16, 0, 0);
            const unsigned short* gb = Wt + (long)(c0 + row) * Kd + kcol;
            __builtin_amdgcn_global_load_lds(
                (const __attribute__((address_space(1))) void*)gb,
                (__attribute__((address_space(3))) void*)(&BsLin[buf][(w * 2 + cc) * 512]),
                16, 0, 0);
        }
    };

    f32x4 acc[4][4] = {};

    stage(0, 0);
    if (nt > 1) stage(1, 1);

    for (int t = 0; t < nt; ++t) {
        const int cur = t & 1;
        // wait for tile t's 4 loads (tile t+1's 4 may still be in flight)
        if (t + 1 < nt) asm volatile("s_waitcnt vmcnt(4)" ::: "memory");
        else            asm volatile("s_waitcnt vmcnt(0)" ::: "memory");
        asm volatile("s_barrier" ::: "memory");   // all waves' tile-t loads landed

        short8 af[4], bv[4];
        #pragma unroll
        for (int m = 0; m < 4; ++m)
            af[m] = *(const short8*)(&AsLin[cur][(wr * 64 + m * 16 + lr) * 32 + lk * 8]);
        #pragma unroll
        for (int n = 0; n < 4; ++n)
            bv[n] = *(const short8*)(&BsLin[cur][(wc * 64 + n * 16 + lr) * 32 + lk * 8]);

        asm volatile("s_waitcnt lgkmcnt(0)" ::: "memory");  // my reads retired
        asm volatile("s_barrier" ::: "memory");             // buffer cur is free

        if (t + 2 < nt) stage(cur, t + 2);   // overwrite freed buffer; flies under MFMA

        #pragma unroll
        for (int m = 0; m < 4; ++m)
            #pragma unroll
            for (int n = 0; n < 4; ++n)
                acc[m][n] = __builtin_amdgcn_mfma_f32_16x16x32_bf16(
                    af[m], bv[n], acc[m][n], 0, 0, 0);
    }

    // epilogue: C/D layout col=lane&15, row=(lane>>4)*4+reg  [m89/m91 verified]
    const int cb = c0 + wc * 64;
    #pragma unroll
    for (int n = 0; n < 4; ++n) {
        const int c = cb + n * 16 + lr;
        const float bc = bias[c];
        #pragma unroll
        for (int m = 0; m < 4; ++m) {
            const long r = r0 + wr * 64 + m * 16 + lk * 4;
            #pragma unroll
            for (int j = 0; j < 4; ++j) {
                float v = acc[m][n][j] + bc;
                if (ACT) v = gelu_f(v);
                if (RESID) v += bf2f(resid[(r + j) * N + c]);
                if (OUT_BF16) ((unsigned short*)Cout)[(r + j) * N + c] = f2bf(v);
                else          ((float*)Cout)[(r + j) * N + c] = v;
            }
        }
    }
}

// ---------------------------------------------------------------------------
// Stage A of LN+pool: each block handles 8 of a mention's 32 rows (1 row/wave),
// LN (ac_ln) + score-weight, writes partial sums. grid = (CH/32)*4.
__global__ __launch_bounds__(512) void ln_pool_part_k(
    const unsigned short* __restrict__ cvb, const float* __restrict__ scores,
    const float* __restrict__ ln_s, const float* __restrict__ ln_b,
    float* __restrict__ partial,   // [CH/32][4][768]
    int mbase)
{
    __shared__ float part[8][768];
    int lm = blockIdx.x >> 2, ks = blockIdx.x & 3;
    int gm = mbase + lm;
    int tid = threadIdx.x, lane = tid & 63, wid = tid >> 6;
    int k = ks * 8 + wid;
    const unsigned short* row = cvb + ((long)lm * 32 + k) * Dq;

    float v[12], gs[12], gb[12];
    float s = 0.f, ss = 0.f;
    #pragma unroll
    for (int j = 0; j < 3; ++j) {
        int col = j * 256 + lane * 4;
        ushort4v u = *(const ushort4v*)(row + col);
        float4 g = *reinterpret_cast<const float4*>(ln_s + col);
        float4 h = *reinterpret_cast<const float4*>(ln_b + col);
        #pragma unroll
        for (int t = 0; t < 4; ++t) {
            float x = bf2f(u[t]);
            v[j * 4 + t] = x;
            s += x; ss += x * x;
        }
        gs[j * 4 + 0] = g.x; gs[j * 4 + 1] = g.y; gs[j * 4 + 2] = g.z; gs[j * 4 + 3] = g.w;
        gb[j * 4 + 0] = h.x; gb[j * 4 + 1] = h.y; gb[j * 4 + 2] = h.z; gb[j * 4 + 3] = h.w;
    }
    #pragma unroll
    for (int off = 32; off > 0; off >>= 1) {
        s  += __shfl_xor(s, off, 64);
        ss += __shfl_xor(ss, off, 64);
    }
    float mu = s * (1.0f / Dq);
    float var = ss * (1.0f / Dq) - mu * mu;
    float rstd = rsqrtf(var + 1e-12f);
    float sc = scores[gm * 32 + k];
    #pragma unroll
    for (int j = 0; j < 3; ++j) {
        int col = j * 256 + lane * 4;
        #pragma unroll
        for (int t = 0; t < 4; ++t)
            part[wid][col + t] = sc * ((v[j * 4 + t] - mu) * rstd * gs[j * 4 + t] + gb[j * 4 + t]);
    }
    __syncthreads();
    for (int d = tid; d < Dq; d += 512) {
        float acc = 0.f;
        #pragma unroll
        for (int w = 0; w < 8; ++w) acc += part[w][d];
        partial[((long)lm * 4 + ks) * Dq + d] = acc;
    }
}

// Stage B: pooled[m] = sum of 4 partials. grid = CH/32.
__global__ __launch_bounds__(256) void ln_pool_comb_k(
    const float* __restrict__ partial, float* __restrict__ pooledf,
    unsigned short* __restrict__ pooledb, int mbase)
{
    int lm = blockIdx.x, gm = mbase + lm;
    int tid = threadIdx.x;
    for (int d = tid; d < Dq; d += 256) {
        const float* p = partial + (long)lm * 4 * Dq + d;
        float s = p[0] + p[Dq] + p[2 * Dq] + p[3 * Dq];
        pooledf[(long)gm * Dq + d] = s;
        pooledb[(long)gm * Dq + d] = f2bf(s);
    }
}

// ---------------------------------------------------------------------------
// Per-mention: y = LN(pu + pooled; pl_ln) * mask; atomicAdd into out[(b,s)] row.
__global__ __launch_bounds__(256) void ln_mask_scatter_k(
    const float* __restrict__ pu, const float* __restrict__ pooled,
    const float* __restrict__ ln_s, const float* __restrict__ ln_b,
    const float* __restrict__ mask,
    const int* __restrict__ bpos, const int* __restrict__ spos,
    float* __restrict__ out)
{
    __shared__ float sm[8];
    int m = blockIdx.x;
    int tid = threadIdx.x;
    float v[3];
    float s = 0.f, ss = 0.f;
    #pragma unroll
    for (int j = 0; j < 3; ++j) {
        int d = tid + j * 256;
        v[j] = pu[(long)m * Dq + d] + pooled[(long)m * Dq + d];
        s += v[j]; ss += v[j] * v[j];
    }
    block_reduce2(s, ss, sm);
    float mu = s * (1.0f / Dq);
    float var = ss * (1.0f / Dq) - mu * mu;
    float rstd = rsqrtf(var + 1e-12f);
    float mk = mask[m];
    long orow = ((long)bpos[m] * Tq + spos[m]) * Dq;
    #pragma unroll
    for (int j = 0; j < 3; ++j) {
        int d = tid + j * 256;
        float y = ((v[j] - mu) * rstd * ln_s[d] + ln_b[d]) * mk;
        atomicAdd(&out[orow + d], y);
    }
}

// ---------------------------------------------------------------------------
// Final in-place LN over each [768] row of out.
__global__ __launch_bounds__(256) void final_ln_k(
    float* __restrict__ out, const float* __restrict__ ln_s,
    const float* __restrict__ ln_b)
{
    __shared__ float sm[8];
    int tid = threadIdx.x;
    float* row = out + (long)blockIdx.x * Dq;
    float v[3];
    float s = 0.f, ss = 0.f;
    #pragma unroll
    for (int j = 0; j < 3; ++j) {
        v[j] = row[tid + j * 256];
        s += v[j]; ss += v[j] * v[j];
    }
    block_reduce2(s, ss, sm);
    float mu = s * (1.0f / Dq);
    float var = ss * (1.0f / Dq) - mu * mu;
    float rstd = rsqrtf(var + 1e-12f);
    #pragma unroll
    for (int j = 0; j < 3; ++j) {
        int d = tid + j * 256;
        row[d] = (v[j] - mu) * rstd * ln_s[d] + ln_b[d];
    }
}

// ---------------------------------------------------------------------------
extern "C" void kernel_launch(void* const* d_in, const int* in_sizes, int n_in,
                              void* d_out, int out_size, void* d_ws, size_t ws_size,
                              hipStream_t stream) {
    const float* enc    = (const float*)d_in[0];
    const float* rv     = (const float*)d_in[1];
    const float* scores = (const float*)d_in[2];
    const int*   bpos   = (const int*)d_in[3];
    const int*   spos   = (const int*)d_in[4];
    const int*   epos   = (const int*)d_in[5];
    const float* mask   = (const float*)d_in[6];
    const float* vp_w   = (const float*)d_in[7];
    const float* vp_b   = (const float*)d_in[8];
    const float* cm_w   = (const float*)d_in[9];
    const float* cm_b   = (const float*)d_in[10];
    const float* cd_w   = (const float*)d_in[11];
    const float* cd_b   = (const float*)d_in[12];
    const float* ac_w1  = (const float*)d_in[13];
    const float* ac_b1  = (const float*)d_in[14];
    const float* ac_w2  = (const float*)d_in[15];
    const float* ac_b2  = (const float*)d_in[16];
    const float* ac_ln_s = (const float*)d_in[17];
    const float* ac_ln_b = (const float*)d_in[18];
    const float* pl_w1  = (const float*)d_in[19];
    const float* pl_b1  = (const float*)d_in[20];
    const float* pl_w2  = (const float*)d_in[21];
    const float* pl_b2  = (const float*)d_in[22];
    const float* pl_ln_s = (const float*)d_in[23];
    const float* pl_ln_b = (const float*)d_in[24];
    const float* ln_s   = (const float*)d_in[25];
    const float* ln_b   = (const float*)d_in[26];
    float* out = (float*)d_out;

    // workspace layout (bytes), ~130 MB of the confirmed 256 MiB
    char* wsb = (char*)d_ws;
    unsigned short* wt_cm = (unsigned short*)wsb; wsb += (size_t)1024 * 256 * 2;
    unsigned short* wt_cd = (unsigned short*)wsb; wsb += (size_t)768 * 1024 * 2;
    unsigned short* wt_a1 = (unsigned short*)wsb; wsb += (size_t)1024 * 768 * 2;
    unsigned short* wt_a2 = (unsigned short*)wsb; wsb += (size_t)768 * 1024 * 2;
    unsigned short* wt_p1 = (unsigned short*)wsb; wsb += (size_t)1024 * 768 * 2;
    unsigned short* wt_p2 = (unsigned short*)wsb; wsb += (size_t)768 * 1024 * 2;
    unsigned short* wt_vp = (unsigned short*)wsb; wsb += (size_t)128 * 1536 * 2;
    unsigned short* pmvb  = (unsigned short*)wsb; wsb += (size_t)Mq * Rq * 2;
    unsigned short* rvb   = (unsigned short*)wsb; wsb += (size_t)NROWS * Rq * 2;
    unsigned short* catenc = (unsigned short*)wsb; wsb += (size_t)Mq * 1536 * 2;
    unsigned short* hb    = (unsigned short*)wsb; wsb += (size_t)CH * Hq * 2;
    unsigned short* tb    = (unsigned short*)wsb; wsb += (size_t)CH * Dq * 2;
    unsigned short* cvb   = (unsigned short*)wsb; wsb += (size_t)CH * Dq * 2;
    float* partial = (float*)wsb; wsb += (size_t)(CH / Kq) * 4 * Dq * 4;
    float* pooledf = (float*)wsb; wsb += (size_t)Mq * Dq * 4;
    unsigned short* pooledb = (unsigned short*)wsb; wsb += (size_t)Mq * Dq * 2;
    float* puf     = (float*)wsb; wsb += (size_t)Mq * Dq * 4;

    // out = encoded_input (base for scatter-add)
    hipMemcpyAsync(out, enc, (size_t)Bq * Tq * Dq * sizeof(float),
                   hipMemcpyDeviceToDevice, stream);

    // weights -> bf16 transposed [N][K]; rv -> bf16
    wtrans_k<<<dim3(1024 / 32, 256 / 32), 256, 0, stream>>>(cm_w, wt_cm, 256, 1024);
    wtrans_k<<<dim3(768 / 32, 1024 / 32), 256, 0, stream>>>(cd_w, wt_cd, 1024, 768);
    wtrans_k<<<dim3(1024 / 32, 768 / 32), 256, 0, stream>>>(ac_w1, wt_a1, 768, 1024);
    wtrans_k<<<dim3(768 / 32, 1024 / 32), 256, 0, stream>>>(ac_w2, wt_a2, 1024, 768);
    wtrans_k<<<dim3(1024 / 32, 768 / 32), 256, 0, stream>>>(pl_w1, wt_p1, 768, 1024);
    wtrans_k<<<dim3(768 / 32, 1024 / 32), 256, 0, stream>>>(pl_w2, wt_p2, 1024, 768);
    wtrans_k<<<dim3(128 / 32, 1536 / 32), 256, 0, stream>>>(vp_w, wt_vp, 1536, 128);
    rv2bf_k<<<(NROWS * Rq) / (256 * 8), 256, 0, stream>>>(rv, rvb);

    // pmv = concat(start,end) @ vp_w + vp_b  as bf16 MFMA GEMM
    gather_enc_k<<<Mq, 192, 0, stream>>>(enc, bpos, spos, epos, catenc);
    mgemm_k<0, 1, 0, 0><<<dim3(Mq / 128, 1), 256, 0, stream>>>(
        catenc, wt_vp, vp_b, pmvb, nullptr, 1536, Rq, nullptr, nullptr, 0);

    for (int c = 0; c < NCH; ++c) {
        int row_base = c * CH;
        int mbase = c * (CH / Kq);
        // h1 = gelu(concat(pmv,rv) @ cm_w + cm_b)   [CH,1024] bf16 (concat fused)
        mgemm_k<1, 1, 0, 1><<<dim3(CH / 128, Hq / 128), 256, 0, stream>>>(
            nullptr, wt_cm, cm_b, hb, nullptr, 2 * Rq, Hq, pmvb, rvb, row_base);
        // t = h1 @ cd_w + cd_b                      [CH,768] bf16
        mgemm_k<0, 1, 0, 0><<<dim3(CH / 128, Dq / 128), 256, 0, stream>>>(
            hb, wt_cd, cd_b, tb, nullptr, Hq, Dq, nullptr, nullptr, 0);
        // h2 = gelu(t @ ac_w1 + ac_b1)              [CH,1024] bf16
        mgemm_k<1, 1, 0, 0><<<dim3(CH / 128, Hq / 128), 256, 0, stream>>>(
            tb, wt_a1, ac_b1, hb, nullptr, Dq, Hq, nullptr, nullptr, 0);
        // cv = h2 @ ac_w2 + ac_b2 + t               [CH,768] bf16
        mgemm_k<0, 1, 1, 0><<<dim3(CH / 128, Dq / 128), 256, 0, stream>>>(
            hb, wt_a2, ac_b2, cvb, tb, Hq, Dq, nullptr, nullptr, 0);
        // LN + score-weighted pool (split-k over 4 blocks/mention, then combine)
        ln_pool_part_k<<<(CH / Kq) * 4, 512, 0, stream>>>(
            cvb, scores, ac_ln_s, ac_ln_b, partial, mbase);
        ln_pool_comb_k<<<CH / Kq, 256, 0, stream>>>(partial, pooledf, pooledb, mbase);
    }

    // pooled MLP
    mgemm_k<1, 1, 0, 0><<<dim3(Mq / 128, Hq / 128), 256, 0, stream>>>(
        pooledb, wt_p1, pl_b1, hb, nullptr, Dq, Hq, nullptr, nullptr, 0);
    mgemm_k<0, 0, 0, 0><<<dim3(Mq / 128, Dq / 128), 256, 0, stream>>>(
        hb, wt_p2, pl_b2, puf, nullptr, Hq, Dq, nullptr, nullptr, 0);

    // LN(pu + pooled) * mask, scatter-add into out
    ln_mask_scatter_k<<<Mq, 256, 0, stream>>>(puf, pooledf, pl_ln_s, pl_ln_b,
                                              mask, bpos, spos, out);

    // final LN over every row of out
    final_ln_k<<<Bq * Tq, 256, 0, stream>>>(out, ln_s, ln_b);
}